// Round 17
// baseline (183.872 us; speedup 1.0000x reference)
//
#include <hip/hip_runtime.h>
#include <math.h>

static constexpr int Bn = 32, Pn = 16384, Cn = 2, Sn = 256;
static constexpr int KXD = 132;   // stored kx lines in ws1 (0..131; >=129 unused)

#define TWO_PI_F 6.28318530717958647692f
#define SPLAT_SCALE 2048.0f
#define SPLAT_INV   (1.0f / 2048.0f)

typedef float v4f __attribute__((ext_vector_type(4)));
typedef short v8s __attribute__((ext_vector_type(8)));

__device__ __forceinline__ float elu_f(float x) {
  return x > 0.0f ? x : (__expf(x) - 1.0f);
}

__device__ __forceinline__ unsigned short f2bf(float x) {
  unsigned int u = __float_as_uint(x);
  u = u + 0x7FFFu + ((u >> 16) & 1u);
  return (unsigned short)(u >> 16);
}

__device__ __forceinline__ int cvt_pk_bf16(float lo, float hi) {
  int r;
  asm("v_cvt_pk_bf16_f32 %0, %1, %2" : "=v"(r) : "v"(lo), "v"(hi));
  return r;
}

// Compiler-only fence: no instructions; forbids reordering/forwarding of LDS
// accesses across it (HW processes a wave's DS ops in order).
__device__ __forceinline__ void wave_lds_fence() {
  __builtin_amdgcn_sched_barrier(0);
  asm volatile("" ::: "memory");
}

// ---- 256-pt FFT on a WAVE-PRIVATE LDS row of interleaved complex float2.
// Barrier-free (fences only); validated rounds 14-16. ------------------------
__device__ __forceinline__ void fft256_c(float2* X, const float2* tw,
                                         int lane, bool inverse) {
  #pragma unroll
  for (int q = 0; q < 4; q++) {
    int t = lane + q * 64;
    int r = (int)(__brev((unsigned)t) >> 24);
    if (t < r) { float2 a = X[t]; X[t] = X[r]; X[r] = a; }
  }
  wave_lds_fence();
  #pragma unroll
  for (int s = 1; s <= 8; s++) {
    int half = 1 << (s - 1);
    #pragma unroll
    for (int q = 0; q < 2; q++) {
      int bf = lane + q * 64;
      int j = bf & (half - 1);
      int grp = bf >> (s - 1);
      int i0 = (grp << s) + j;
      int i1 = i0 + half;
      float2 w = tw[j << (8 - s)];
      float wi = inverse ? -w.y : w.y;
      float2 x1 = X[i1];
      float tr = fmaf(x1.x, w.x, -x1.y * wi);
      float ti = fmaf(x1.x, wi,  x1.y * w.x);
      float2 x0 = X[i0];
      X[i0] = make_float2(x0.x + tr, x0.y + ti);
      X[i1] = make_float2(x0.x - tr, x0.y - ti);
    }
    wave_lds_fence();
  }
}

// ---------------- enc precompute: encpart[p][64] = enc(p) @ W_in[0:60] ------
__global__ __launch_bounds__(64) void enc_kernel(const float* __restrict__ mp,
                                                 const float* __restrict__ W_in,
                                                 float* __restrict__ encpart) {
  const float freqs[10] = {1.0f, 1.71448797f, 2.93946898f, 5.03968420f,
                           8.64050360f, 14.8140558f, 25.3984847f,
                           43.5454520f, 74.6580997f, 128.0f};
  __shared__ float ebuf[60][64];
  int tid = threadIdx.x;
  int p = blockIdx.x * 64 + tid;
  #pragma unroll
  for (int c = 0; c < 3; c++) {
    float pos = mp[p * 3 + c];
    #pragma unroll
    for (int i = 0; i < 10; i++) {
      float ang = (TWO_PI_F * pos) * freqs[i];
      ebuf[c * 20 + i][tid]      = sinf(ang);
      ebuf[c * 20 + 10 + i][tid] = cosf(ang);
    }
  }
  float h[64];
  #pragma unroll
  for (int j = 0; j < 64; j++) h[j] = 0.0f;
  for (int k = 0; k < 60; k++) {
    float ek = ebuf[k][tid];
    const float* wr = W_in + k * 64;
    #pragma unroll
    for (int j = 0; j < 64; j++) h[j] = fmaf(ek, wr[j], h[j]);
  }
  float* o = encpart + (size_t)p * 64;
  #pragma unroll
  for (int j = 0; j < 64; j++) o[j] = h[j];
}

// ------- prep: zpart[b][64], W^T A-fragments (bf16), zero stripCntSeg -------
__global__ __launch_bounds__(256) void prep_kernel(const float* __restrict__ z,
                                                   const float* __restrict__ W_in,
                                                   const float* __restrict__ W_layers,
                                                   float* __restrict__ zpart,
                                                   unsigned short* __restrict__ Wfrag,
                                                   int* __restrict__ stripCntSeg) {
  int idx = blockIdx.x * 256 + threadIdx.x;     // 0..4095
  stripCntSeg[idx] = 0;                          // Bn*8*16 = 4096 ints
  if (idx < 2048) {
    int b = idx >> 6, j = idx & 63;
    float s = 0.0f;
    #pragma unroll
    for (int k = 0; k < 10; k++) s = fmaf(z[b * 10 + k], W_in[(60 + k) * 64 + j], s);
    zpart[b * 64 + j] = s;
  } else {
    int t2 = idx - 2048;
    int L = t2 >> 9, m = (t2 >> 7) & 3, s = (t2 >> 6) & 1, lane = t2 & 63;
    #pragma unroll
    for (int i = 0; i < 8; i++) {
      int k = s * 32 + ((lane >> 4) * 8) + i;
      int j = m * 16 + (lane & 15);
      Wfrag[(size_t)t2 * 8 + i] = f2bf(W_layers[L * 4096 + k * 64 + j]);
    }
  }
}

// ---- D->B regroup: fixed lane-group gather (verified rounds 4-16) ----
__device__ __forceinline__ void regroup(const v4f* acc, v8s* Bf,
                                        int srcA, int srcB, bool hi) {
  union U4 { int u[4]; v8s v; };
  int pk[4][2];
  #pragma unroll
  for (int m = 0; m < 4; m++) {
    pk[m][0] = cvt_pk_bf16(acc[m][0], acc[m][1]);
    pk[m][1] = cvt_pk_bf16(acc[m][2], acc[m][3]);
  }
  #pragma unroll
  for (int s = 0; s < 2; s++) {
    int t00 = __builtin_amdgcn_ds_bpermute(srcA, pk[2 * s][0]);
    int t01 = __builtin_amdgcn_ds_bpermute(srcA, pk[2 * s + 1][0]);
    int t10 = __builtin_amdgcn_ds_bpermute(srcA, pk[2 * s][1]);
    int t11 = __builtin_amdgcn_ds_bpermute(srcA, pk[2 * s + 1][1]);
    int t20 = __builtin_amdgcn_ds_bpermute(srcB, pk[2 * s][0]);
    int t21 = __builtin_amdgcn_ds_bpermute(srcB, pk[2 * s + 1][0]);
    int t30 = __builtin_amdgcn_ds_bpermute(srcB, pk[2 * s][1]);
    int t31 = __builtin_amdgcn_ds_bpermute(srcB, pk[2 * s + 1][1]);
    U4 u;
    u.u[0] = hi ? t01 : t00;
    u.u[1] = hi ? t11 : t10;
    u.u[2] = hi ? t21 : t20;
    u.u[3] = hi ? t31 : t30;
    Bf[s] = u.v;
  }
}

// ------- all-register MFMA MLP, 32 points/wave, Af software pipeline --------
__global__ __launch_bounds__(256) void mlp_mfma32_kernel(
    const float* __restrict__ encpart, const float* __restrict__ zpart,
    const unsigned short* __restrict__ Wfrag,
    const float* __restrict__ W_out1, const float* __restrict__ W_out2,
    const float* __restrict__ mp, const float* __restrict__ orient,
    const float* __restrict__ amp, const float* __restrict__ ampvar,
    float4* __restrict__ rec, int* __restrict__ stripCntSeg,
    float* __restrict__ out_fp, float* __restrict__ out_disp) {
  __shared__ int h16[16];
  int tid = threadIdx.x;
  int lane = tid & 63;
  int wave = tid >> 6;
  int wid = blockIdx.x * 4 + wave;            // 0..16383
  int b = __builtin_amdgcn_readfirstlane(wid >> 9);
  int pbase = (wid & 511) * 32;
  int g = lane >> 4;
  int p0 = pbase + (lane & 15);
  int p1 = p0 + 16;

  if (tid < 16) h16[tid] = 0;
  __syncthreads();

  union U4 { int u[4]; v8s v; };

  v8s Bf0[2], Bf1[2];
  #pragma unroll
  for (int s = 0; s < 2; s++) {
    int k0 = s * 32 + g * 8;
    const float4* z4 = (const float4*)(zpart + b * 64 + k0);
    float4 z0 = z4[0], z1 = z4[1];
    {
      const float4* e4 = (const float4*)(encpart + (size_t)p0 * 64 + k0);
      float4 e0 = e4[0], e1 = e4[1];
      U4 u;
      u.u[0] = cvt_pk_bf16(e0.x + z0.x, e0.y + z0.y);
      u.u[1] = cvt_pk_bf16(e0.z + z0.z, e0.w + z0.w);
      u.u[2] = cvt_pk_bf16(e1.x + z1.x, e1.y + z1.y);
      u.u[3] = cvt_pk_bf16(e1.z + z1.z, e1.w + z1.w);
      Bf0[s] = u.v;
    }
    {
      const float4* e4 = (const float4*)(encpart + (size_t)p1 * 64 + k0);
      float4 e0 = e4[0], e1 = e4[1];
      U4 u;
      u.u[0] = cvt_pk_bf16(e0.x + z0.x, e0.y + z0.y);
      u.u[1] = cvt_pk_bf16(e0.z + z0.z, e0.w + z0.w);
      u.u[2] = cvt_pk_bf16(e1.x + z1.x, e1.y + z1.y);
      u.u[3] = cvt_pk_bf16(e1.z + z1.z, e1.w + z1.w);
      Bf1[s] = u.v;
    }
  }

  int srcA = ((((lane >> 4) & 1) * 32) + (lane & 15)) << 2;
  int srcB = srcA + 64;
  bool hi = (lane >> 5) & 1;

  const v8s* WfragV = (const v8s*)Wfrag;
  v4f acc0[4], acc1[4];

  // prologue: layer-0 weight fragments
  v8s Af[4][2];
  #pragma unroll
  for (int m = 0; m < 4; m++)
    #pragma unroll
    for (int s = 0; s < 2; s++)
      Af[m][s] = WfragV[(size_t)((m * 2 + s) * 64) + lane];

  #pragma unroll 1
  for (int L = 0; L < 4; L++) {
    // issue next layer's Af loads FIRST (vmcnt stays in flight across the
    // lgkm-only MFMA/ELU/regroup phase below)
    v8s AfN[4][2];
    if (L < 3) {
      #pragma unroll
      for (int m = 0; m < 4; m++)
        #pragma unroll
        for (int s = 0; s < 2; s++)
          AfN[m][s] = WfragV[(size_t)((((L + 1) * 4 + m) * 2 + s) * 64) + lane];
    }

    #pragma unroll
    for (int m = 0; m < 4; m++) {
      acc0[m] = (v4f){0.f, 0.f, 0.f, 0.f};
      acc1[m] = (v4f){0.f, 0.f, 0.f, 0.f};
    }
    #pragma unroll
    for (int s = 0; s < 2; s++) {
      #pragma unroll
      for (int m = 0; m < 4; m++)
        acc0[m] = __builtin_amdgcn_mfma_f32_16x16x32_bf16(Af[m][s], Bf0[s], acc0[m], 0, 0, 0);
      #pragma unroll
      for (int m = 0; m < 4; m++)
        acc1[m] = __builtin_amdgcn_mfma_f32_16x16x32_bf16(Af[m][s], Bf1[s], acc1[m], 0, 0, 0);
    }

    #pragma unroll
    for (int m = 0; m < 4; m++)
      #pragma unroll
      for (int r = 0; r < 4; r++) {
        acc0[m][r] = elu_f(acc0[m][r]);
        acc1[m][r] = elu_f(acc1[m][r]);
      }

    if (L < 3) {
      regroup(acc0, Bf0, srcA, srcB, hi);
      regroup(acc1, Bf1, srcA, srcB, hi);
      #pragma unroll
      for (int m = 0; m < 4; m++)
        #pragma unroll
        for (int s = 0; s < 2; s++)
          Af[m][s] = AfN[m][s];
    }
  }

  float o00 = 0.f, o01 = 0.f, o02 = 0.f;
  float o10 = 0.f, o11 = 0.f, o12 = 0.f;
  #pragma unroll
  for (int m = 0; m < 4; m++) {
    int jb = m * 16 + g * 4;
    const float4* w4 = (const float4*)(W_out1 + jb * 3);
    float4 wa = w4[0], wb = w4[1], wc = w4[2];
    o00 += acc0[m][0] * wa.x + acc0[m][1] * wa.w + acc0[m][2] * wb.z + acc0[m][3] * wc.y;
    o01 += acc0[m][0] * wa.y + acc0[m][1] * wb.x + acc0[m][2] * wb.w + acc0[m][3] * wc.z;
    o02 += acc0[m][0] * wa.z + acc0[m][1] * wb.y + acc0[m][2] * wc.x + acc0[m][3] * wc.w;
    o10 += acc1[m][0] * wa.x + acc1[m][1] * wa.w + acc1[m][2] * wb.z + acc1[m][3] * wc.y;
    o11 += acc1[m][0] * wa.y + acc1[m][1] * wb.x + acc1[m][2] * wb.w + acc1[m][3] * wc.z;
    o12 += acc1[m][0] * wa.z + acc1[m][1] * wb.y + acc1[m][2] * wc.x + acc1[m][3] * wc.w;
  }
  o00 += __shfl_xor(o00, 16, 64); o00 += __shfl_xor(o00, 32, 64);
  o01 += __shfl_xor(o01, 16, 64); o01 += __shfl_xor(o01, 32, 64);
  o02 += __shfl_xor(o02, 16, 64); o02 += __shfl_xor(o02, 32, 64);
  o10 += __shfl_xor(o10, 16, 64); o10 += __shfl_xor(o10, 32, 64);
  o11 += __shfl_xor(o11, 16, 64); o11 += __shfl_xor(o11, 32, 64);
  o12 += __shfl_xor(o12, 16, 64); o12 += __shfl_xor(o12, 32, 64);

  o00 = elu_f(o00); o01 = elu_f(o01); o02 = elu_f(o02);
  o10 = elu_f(o10); o11 = elu_f(o11); o12 = elu_f(o12);

  float W0 = W_out2[0], W1 = W_out2[1], W2 = W_out2[2];
  float W3 = W_out2[3], W4 = W_out2[4], W5 = W_out2[5];
  float W6 = W_out2[6], W7 = W_out2[7], W8 = W_out2[8];

  float d00 = o00 * W0 + o01 * W3 + o02 * W6;
  float d01 = o00 * W1 + o01 * W4 + o02 * W7;
  float d02 = o00 * W2 + o01 * W5 + o02 * W8;
  float d10 = o10 * W0 + o11 * W3 + o12 * W6;
  float d11 = o10 * W1 + o11 * W4 + o12 * W7;
  float d12 = o10 * W2 + o11 * W5 + o12 * W8;

  float m00 = mp[p0 * 3 + 0], m01 = mp[p0 * 3 + 1], m02 = mp[p0 * 3 + 2];
  float m10 = mp[p1 * 3 + 0], m11 = mp[p1 * 3 + 1], m12 = mp[p1 * 3 + 2];
  float f00 = m00 + d00, f01 = m01 + d01, f02 = m02 + d02;
  float f10 = m10 + d10, f11 = m11 + d11, f12 = m12 + d12;

  size_t ob0 = ((size_t)b * Pn + p0) * 3;
  size_t ob1 = ((size_t)b * Pn + p1) * 3;
  if (g == 2) {
    out_disp[ob0 + 0] = d00; out_disp[ob0 + 1] = d01; out_disp[ob0 + 2] = d02;
    out_fp[ob0 + 0] = f00; out_fp[ob0 + 1] = f01; out_fp[ob0 + 2] = f02;
  }
  if (g == 3) {
    out_disp[ob1 + 0] = d10; out_disp[ob1 + 1] = d11; out_disp[ob1 + 2] = d12;
    out_fp[ob1 + 0] = f10; out_fp[ob1 + 1] = f11; out_fp[ob1 + 2] = f12;
  }

  const float* R = orient + b * 9;
  float px0 = R[0] * f00 + R[1] * f01 + R[2] * f02;
  float py0 = R[3] * f00 + R[4] * f01 + R[5] * f02;
  float px1 = R[0] * f10 + R[1] * f11 + R[2] * f12;
  float py1 = R[3] * f10 + R[4] * f11 + R[5] * f12;

  float a00 = ampvar[p0], a01 = ampvar[Pn + p0];
  float mx0 = fmaxf(a00, a01);
  float e00 = __expf(a00 - mx0), e01 = __expf(a01 - mx0);
  float inv0 = 1.0f / (e00 + e01);
  float w00a = amp[p0] * e00 * inv0;
  float w01a = amp[Pn + p0] * e01 * inv0;
  float a10 = ampvar[p1], a11 = ampvar[Pn + p1];
  float mx1 = fmaxf(a10, a11);
  float e10 = __expf(a10 - mx1), e11 = __expf(a11 - mx1);
  float inv1 = 1.0f / (e10 + e11);
  float w10a = amp[p1] * e10 * inv1;
  float w11a = amp[Pn + p1] * e11 * inv1;

  float pxp0 = fminf(fmaxf((px0 + 0.5f) * 256.0f, 0.0f), 254.999f);
  float pyp0 = fminf(fmaxf((py0 + 0.5f) * 256.0f, 0.0f), 254.999f);
  float pxp1 = fminf(fmaxf((px1 + 0.5f) * 256.0f, 0.0f), 254.999f);
  float pyp1 = fminf(fmaxf((py1 + 0.5f) * 256.0f, 0.0f), 254.999f);

  if (g == 0) {
    atomicAdd(&h16[((int)pyp0) >> 4], 1);
    rec[(size_t)b * Pn + p0] = make_float4(pxp0, pyp0, w00a, w01a);
  }
  if (g == 1) {
    atomicAdd(&h16[((int)pyp1) >> 4], 1);
    rec[(size_t)b * Pn + p1] = make_float4(pxp1, pyp1, w10a, w11a);
  }
  __syncthreads();
  int bblk = __builtin_amdgcn_readfirstlane(blockIdx.x >> 7);
  int seg  = __builtin_amdgcn_readfirstlane((blockIdx.x & 127) >> 4);
  if (tid < 16 && h16[tid] != 0)
    atomicAdd(&stripCntSeg[(bblk * 8 + seg) * 16 + tid], h16[tid]);
}

// -------- scatter16: per-(b,seg), group records by y-strip (LDS cursors) ----
__global__ __launch_bounds__(256) void scatter16_kernel(const float4* __restrict__ rec,
                                                        const int* __restrict__ stripCntSeg,
                                                        float4* __restrict__ sorted) {
  __shared__ int tot[16], start[16], cur[16];
  int blk = blockIdx.x;
  int b = blk >> 3, seg = blk & 7;
  int tid = threadIdx.x;
  int myoff = 0;
  if (tid < 16) {
    int acc = 0, so = 0;
    #pragma unroll
    for (int s = 0; s < 8; s++) {
      int c = stripCntSeg[(b * 8 + s) * 16 + tid];
      if (s < seg) so += c;
      acc += c;
    }
    tot[tid] = acc; myoff = so;
  }
  __syncthreads();
  if (tid == 0) { int a = 0; for (int i = 0; i < 16; i++) { start[i] = a; a += tot[i]; } }
  __syncthreads();
  if (tid < 16) cur[tid] = start[tid] + myoff;
  __syncthreads();
  int base = seg * 2048;
  for (int i = base + tid; i < base + 2048; i += 256) {
    float4 r = rec[(size_t)b * Pn + i];
    int strip = ((int)r.y) >> 4;
    int slot = atomicAdd(&cur[strip], 1);
    sorted[(size_t)b * Pn + slot] = r;
  }
}

// ------- F1 (fused splat + row FFT): block = (b, 8-row chunk), 1024 blocks.
// Strip-sorted contiguous reads (strips [(8c-1)>>4, (8c+7)>>4]); native int
// LDS atomics (fixed-point x2048) aliased onto the complex buffer; per-wave
// fence-only float2 FFTs (2/wave); Hermitian unpack; transposed write [kx][y].
__global__ __launch_bounds__(256) void splat_fft_rows_T(const float4* __restrict__ sorted,
                                                        const int* __restrict__ stripCntSeg,
                                                        float2* __restrict__ ws1) {
  __shared__ float2 scx[8][257];
  __shared__ float2 tw[128];
  __shared__ int tot[16], start[16];
  int tid = threadIdx.x;
  int lane = tid & 63, wave = tid >> 6;
  int blk = blockIdx.x;
  int chunk = blk & 31, b = blk >> 5;
  for (int t = tid; t < 128; t += 256) {
    float ang = -TWO_PI_F * (float)t / 256.0f;
    tw[t] = make_float2(cosf(ang), sinf(ang));
  }
  if (tid < 16) {
    int acc = 0;
    #pragma unroll
    for (int s = 0; s < 8; s++) acc += stripCntSeg[(b * 8 + s) * 16 + tid];
    tot[tid] = acc;
  }
  float2* fc = &scx[0][0];
  int* ip = (int*)fc;
  for (int j = tid; j < 8 * 257; j += 256) fc[j] = make_float2(0.f, 0.f);
  __syncthreads();
  if (tid == 0) { int a = 0; for (int i = 0; i < 16; i++) { start[i] = a; a += tot[i]; } }
  __syncthreads();

  int ybase = chunk * 8;
  int loS = (chunk > 0) ? ((ybase - 1) >> 4) : 0;
  int hiS = (ybase + 7) >> 4;
  int lo = start[loS];
  int hi = start[hiS] + tot[hiS];
  const float4* rb = sorted + (size_t)b * Pn;
  for (int i = lo + tid; i < hi; i += 256) {
    float4 r = rb[i];
    int y0 = (int)r.y;
    int d = y0 - ybase;
    if (d >= -1 && d <= 7) {
      int x0 = (int)r.x;
      int x1 = x0 + 1;                       // x0 <= 254 by clamp
      float fx = r.x - (float)x0, fy = r.y - (float)y0;
      float w00 = (1.f - fx) * (1.f - fy), w10 = fx * (1.f - fy);
      float w01 = (1.f - fx) * fy,         w11 = fx * fy;
      if (d >= 0) {
        int e0 = (d * 257 + x0) * 2, e1 = (d * 257 + x1) * 2;
        atomicAdd(&ip[e0],     __float2int_rn(r.z * w00 * SPLAT_SCALE));
        atomicAdd(&ip[e0 + 1], __float2int_rn(r.w * w00 * SPLAT_SCALE));
        atomicAdd(&ip[e1],     __float2int_rn(r.z * w10 * SPLAT_SCALE));
        atomicAdd(&ip[e1 + 1], __float2int_rn(r.w * w10 * SPLAT_SCALE));
      }
      if (d <= 6) {
        int e0 = ((d + 1) * 257 + x0) * 2, e1 = ((d + 1) * 257 + x1) * 2;
        atomicAdd(&ip[e0],     __float2int_rn(r.z * w01 * SPLAT_SCALE));
        atomicAdd(&ip[e0 + 1], __float2int_rn(r.w * w01 * SPLAT_SCALE));
        atomicAdd(&ip[e1],     __float2int_rn(r.z * w11 * SPLAT_SCALE));
        atomicAdd(&ip[e1 + 1], __float2int_rn(r.w * w11 * SPLAT_SCALE));
      }
    }
  }
  __syncthreads();
  for (int j = tid; j < 8 * 257; j += 256) {
    int2 v = ((const int2*)ip)[j];
    fc[j] = make_float2((float)v.x * SPLAT_INV, (float)v.y * SPLAT_INV);
  }
  __syncthreads();

  // 2 wave-private FFTs per wave, fence-only, complex layout
  #pragma unroll 1
  for (int rnd = 0; rnd < 2; rnd++) {
    int row = wave * 2 + rnd;
    fft256_c(&scx[row][0], tw, lane, false);
  }
  __syncthreads();
  // unpack: Z0 = (Z(k)+conj(Z(m)))/2, Z1 = -i/2 (Z(k)-conj(Z(m))), m=(256-k)&255
  #pragma unroll 1
  for (int ko = 0; ko < 5; ko++) {
    int kx = ko * 32 + (tid >> 3);
    int ysub = tid & 7;
    if (kx < KXD) {
      int m = (256 - kx) & 255;
      float2 zv = scx[ysub][kx];
      float2 mv = scx[ysub][m];
      float z0r = 0.5f * (zv.x + mv.x), z0i = 0.5f * (zv.y - mv.y);
      float z1r = 0.5f * (zv.y + mv.y), z1i = 0.5f * (mv.x - zv.x);
      size_t y = (size_t)(chunk * 8 + ysub);
      ws1[((size_t)(b * 2 + 0) * KXD + kx) * 256 + y] = make_float2(z0r, z0i);
      ws1[((size_t)(b * 2 + 1) * KXD + kx) * 256 + y] = make_float2(z1r, z1i);
    }
  }
}

// ------- F2: per kx line: fwd y-FFT both classes, filter-combine, phase_y,
//         inv y-FFT; write line kx AND conjugate mirror, transposed [y][kx] --
__global__ __launch_bounds__(256) void fft_mid_T(const float2* __restrict__ ws1,
                                                 float2* __restrict__ A2,
                                                 const float* __restrict__ shift,
                                                 const float* __restrict__ Aarr,
                                                 const float* __restrict__ Bparr) {
  __shared__ float2 scx[4][257], wcx[4][257];
  __shared__ float2 tw[128];
  int tid = threadIdx.x;
  int lane = tid & 63, wave = tid >> 6;
  int blk = blockIdx.x;
  int b = blk / 33, c33 = blk % 33;
  int kx = c33 * 4 + wave;                   // 0..131
  for (int t = tid; t < 128; t += 256) {
    float ang = -TWO_PI_F * (float)t / 256.0f;
    tw[t] = make_float2(cosf(ang), sinf(ang));
  }
  __syncthreads();
  float A0 = Aarr[0], A1 = Aarr[1], B0 = Bparr[0], B1 = Bparr[1];
  float sy = shift[b * 2 + 1];
  const float2* r0 = ws1 + ((size_t)(b * 2 + 0) * KXD + kx) * 256;
  const float2* r1 = ws1 + ((size_t)(b * 2 + 1) * KXD + kx) * 256;
  #pragma unroll
  for (int q = 0; q < 4; q++) {
    int i = lane + q * 64;
    scx[wave][i] = r0[i];
    wcx[wave][i] = r1[i];
  }
  wave_lds_fence();
  fft256_c(&scx[wave][0], tw, lane, false);
  fft256_c(&wcx[wave][0], tw, lane, false);
  float rx = (kx <= 128) ? (float)kx : (float)(256 - kx);
  #pragma unroll
  for (int q = 0; q < 4; q++) {
    int ky = lane + q * 64;
    float ry = (ky <= 128) ? (float)ky : (float)(256 - ky);
    float R = sqrtf(rx * rx + ry * ry);
    float FF0 = A0 * A0 * __expf(-B0 * B0 * R);
    float FF1 = A1 * A1 * __expf(-B1 * B1 * R);
    float2 sv = scx[wave][ky];
    float2 wv = wcx[wave][ky];
    float Gr = FF0 * sv.x + FF1 * wv.x;
    float Gi = FF0 * sv.y + FF1 * wv.y;
    float fk = (float)((ky < 128) ? ky : ky - 256) / 256.0f;
    float th = -TWO_PI_F * fk * sy;
    float cc = __cosf(th), ss = __sinf(th);
    scx[wave][ky] = make_float2(Gr * cc - Gi * ss, Gr * ss + Gi * cc);
  }
  wave_lds_fence();
  fft256_c(&scx[wave][0], tw, lane, true);
  __syncthreads();   // cross-wave transposed write below
  const float inv = 1.0f / 256.0f;
  int kx0 = c33 * 4;
  #pragma unroll 1
  for (int yo = 0; yo < 4; yo++) {
    int ksub = tid & 3;
    int y = yo * 64 + (tid >> 2);
    int kxw = kx0 + ksub;
    float2 v = scx[ksub][y];
    float vr = v.x * inv, vi = v.y * inv;
    if (kxw <= 128)
      A2[(size_t)b * 65536 + (size_t)y * 256 + kxw] = make_float2(vr, vi);
    if (kxw >= 1 && kxw <= 127)
      A2[(size_t)b * 65536 + (size_t)y * 256 + (256 - kxw)] = make_float2(vr, -vi);
  }
}

// ------- F3: packed pair inverse x-FFT (Hermitian projection via shuffles) --
__global__ __launch_bounds__(256) void fft_final_pk(const float2* __restrict__ A2t,
                                                    const float* __restrict__ shift,
                                                    float* __restrict__ out_imgs) {
  __shared__ float2 X[4][257];
  __shared__ float2 tw[128];
  int tid = threadIdx.x;
  int lane = tid & 63, wave = tid >> 6;
  int blk = blockIdx.x;
  int b = blk >> 5, grp = blk & 31;
  int y0 = grp * 8 + wave * 2;
  int y1 = y0 + 1;
  for (int t = tid; t < 128; t += 256) {
    float ang = -TWO_PI_F * (float)t / 256.0f;
    tw[t] = make_float2(cosf(ang), sinf(ang));
  }
  __syncthreads();   // twiddles written by waves 0-1, read by all
  float sx = shift[b * 2 + 0];
  const float2* row0 = A2t + (size_t)b * 65536 + (size_t)y0 * 256;
  const float2* row1 = A2t + (size_t)b * 65536 + (size_t)y1 * 256;
  float g0r[4], g0i[4], g1r[4], g1i[4];
  #pragma unroll
  for (int q = 0; q < 4; q++) {
    int k = lane + q * 64;
    float2 v0 = row0[k], v1 = row1[k];
    float fk = (float)((k < 128) ? k : k - 256) / 256.0f;
    float th = -TWO_PI_F * fk * sx;
    float c = __cosf(th), s = __sinf(th);
    g0r[q] = v0.x * c - v0.y * s;  g0i[q] = v0.x * s + v0.y * c;
    g1r[q] = v1.x * c - v1.y * s;  g1i[q] = v1.x * s + v1.y * c;
  }
  int src = (64 - lane) & 63;
  float s0r[4], s0i[4], s1r[4], s1i[4];
  #pragma unroll
  for (int j = 0; j < 4; j++) {
    s0r[j] = __shfl(g0r[j], src, 64);  s0i[j] = __shfl(g0i[j], src, 64);
    s1r[j] = __shfl(g1r[j], src, 64);  s1i[j] = __shfl(g1i[j], src, 64);
  }
  bool l0 = (lane == 0);
  #pragma unroll
  for (int q = 0; q < 4; q++) {
    const int qa = 3 - q;          // lane >= 1
    const int qb = (4 - q) & 3;    // lane == 0
    float m0r = l0 ? s0r[qb] : s0r[qa];
    float m0i = l0 ? s0i[qb] : s0i[qa];
    float m1r = l0 ? s1r[qb] : s1r[qa];
    float m1i = l0 ? s1i[qb] : s1i[qa];
    float h0r = 0.5f * (g0r[q] + m0r), h0i = 0.5f * (g0i[q] - m0i);
    float h1r = 0.5f * (g1r[q] + m1r), h1i = 0.5f * (g1i[q] - m1i);
    int k = lane + q * 64;
    X[wave][k] = make_float2(h0r - h1i, h0i + h1r);   // pack: hg0 + i*hg1
  }
  wave_lds_fence();
  fft256_c(&X[wave][0], tw, lane, true);
  const float inv = 1.0f / 256.0f;
  float* o0 = out_imgs + (size_t)b * 65536 + (size_t)y0 * 256;
  float* o1 = out_imgs + (size_t)b * 65536 + (size_t)y1 * 256;
  #pragma unroll
  for (int q = 0; q < 4; q++) {
    int x = lane + q * 64;
    float2 v = X[wave][x];
    o0[x] = v.x * inv;
    o1[x] = v.y * inv;
  }
}

// ---------------- launch ----------------
extern "C" void kernel_launch(void* const* d_in, const int* in_sizes, int n_in,
                              void* d_out, int out_size, void* d_ws, size_t ws_size,
                              hipStream_t stream) {
  (void)in_sizes; (void)n_in; (void)out_size; (void)ws_size;
  const float* z       = (const float*)d_in[0];
  const float* orient  = (const float*)d_in[1];
  const float* shift   = (const float*)d_in[2];
  const float* mp      = (const float*)d_in[3];
  const float* W_in    = (const float*)d_in[4];
  const float* W_layers= (const float*)d_in[5];
  const float* W_out1  = (const float*)d_in[6];
  const float* W_out2  = (const float*)d_in[7];
  const float* amp     = (const float*)d_in[8];
  const float* ampvar  = (const float*)d_in[9];
  const float* Aarr    = (const float*)d_in[10];
  const float* Bparr   = (const float*)d_in[11];

  char* ws0 = (char*)d_ws;
  // Region0 (sequential lifetimes): encpart(4MB, enc->mlp) -> A2(16.8MB, F2->F3)
  float*  encpart = (float*)ws0;
  float2* A2      = (float2*)ws0;
  // RegionB at +19MiB; all buffers disjoint.
  char* wsB = ws0 + 19922944;
  float2* ws1     = (float2*)wsB;                         // 17,301,504 B (F1->F2)
  float4* rec     = (float4*)(wsB + 17301504);            // 8 MiB (mlp->scatter)
  float4* sorted  = (float4*)(wsB + 25690112);            // 8 MiB (scatter->F1)
  float*  zpart   = (float*)(wsB + 34078720);             // 8 KB
  unsigned short* Wfrag = (unsigned short*)(wsB + 34078720 + 8192);  // 32 KB
  int* stripCntSeg = (int*)(wsB + 34078720 + 40960);      // 16 KB

  float* out      = (float*)d_out;
  float* out_imgs = out;                               // [B][S][S]
  float* out_fp   = out + (size_t)Bn * Sn * Sn;        // [B][P][3]
  float* out_disp = out_fp + (size_t)Bn * Pn * 3;      // [B][P][3]

  enc_kernel<<<Pn / 64, 64, 0, stream>>>(mp, W_in, encpart);
  prep_kernel<<<16, 256, 0, stream>>>(z, W_in, W_layers, zpart, Wfrag, stripCntSeg);
  mlp_mfma32_kernel<<<(Bn * Pn / 32) / 4, 256, 0, stream>>>(
      encpart, zpart, Wfrag, W_out1, W_out2, mp, orient, amp, ampvar,
      rec, stripCntSeg, out_fp, out_disp);
  scatter16_kernel<<<Bn * 8, 256, 0, stream>>>(rec, stripCntSeg, sorted);
  splat_fft_rows_T<<<Bn * 32, 256, 0, stream>>>(sorted, stripCntSeg, ws1);
  fft_mid_T<<<Bn * 33, 256, 0, stream>>>(ws1, A2, shift, Aarr, Bparr);
  fft_final_pk<<<Bn * 32, 256, 0, stream>>>(A2, shift, out_imgs);
}

// Round 18
// 173.481 us; speedup vs baseline: 1.0599x; 1.0599x over previous
//
#include <hip/hip_runtime.h>
#include <math.h>

static constexpr int Bn = 32, Pn = 16384, Cn = 2, Sn = 256;
static constexpr int KXD = 132;   // stored kx lines in ws1 (0..131; >=129 unused)

#define TWO_PI_F 6.28318530717958647692f
#define SPLAT_SCALE 2048.0f
#define SPLAT_INV   (1.0f / 2048.0f)

typedef float v4f __attribute__((ext_vector_type(4)));
typedef short v8s __attribute__((ext_vector_type(8)));

__device__ __forceinline__ float elu_f(float x) {
  return x > 0.0f ? x : (__expf(x) - 1.0f);
}

__device__ __forceinline__ unsigned short f2bf(float x) {
  unsigned int u = __float_as_uint(x);
  u = u + 0x7FFFu + ((u >> 16) & 1u);
  return (unsigned short)(u >> 16);
}

__device__ __forceinline__ int cvt_pk_bf16(float lo, float hi) {
  int r;
  asm("v_cvt_pk_bf16_f32 %0, %1, %2" : "=v"(r) : "v"(lo), "v"(hi));
  return r;
}

// Compiler-only fence: no instructions; forbids reordering/forwarding of LDS
// accesses across it (HW processes a wave's DS ops in order).
__device__ __forceinline__ void wave_lds_fence() {
  __builtin_amdgcn_sched_barrier(0);
  asm volatile("" ::: "memory");
}

// ---- 256-pt FFT on a WAVE-PRIVATE LDS row of interleaved complex float2.
// Barrier-free (fences only); validated rounds 14-17. ------------------------
__device__ __forceinline__ void fft256_c(float2* X, const float2* tw,
                                         int lane, bool inverse) {
  #pragma unroll
  for (int q = 0; q < 4; q++) {
    int t = lane + q * 64;
    int r = (int)(__brev((unsigned)t) >> 24);
    if (t < r) { float2 a = X[t]; X[t] = X[r]; X[r] = a; }
  }
  wave_lds_fence();
  #pragma unroll
  for (int s = 1; s <= 8; s++) {
    int half = 1 << (s - 1);
    #pragma unroll
    for (int q = 0; q < 2; q++) {
      int bf = lane + q * 64;
      int j = bf & (half - 1);
      int grp = bf >> (s - 1);
      int i0 = (grp << s) + j;
      int i1 = i0 + half;
      float2 w = tw[j << (8 - s)];
      float wi = inverse ? -w.y : w.y;
      float2 x1 = X[i1];
      float tr = fmaf(x1.x, w.x, -x1.y * wi);
      float ti = fmaf(x1.x, wi,  x1.y * w.x);
      float2 x0 = X[i0];
      X[i0] = make_float2(x0.x + tr, x0.y + ti);
      X[i1] = make_float2(x0.x - tr, x0.y - ti);
    }
    wave_lds_fence();
  }
}

// ---------------- enc precompute: encpart[p][64] = enc(p) @ W_in[0:60] ------
__global__ __launch_bounds__(64) void enc_kernel(const float* __restrict__ mp,
                                                 const float* __restrict__ W_in,
                                                 float* __restrict__ encpart) {
  const float freqs[10] = {1.0f, 1.71448797f, 2.93946898f, 5.03968420f,
                           8.64050360f, 14.8140558f, 25.3984847f,
                           43.5454520f, 74.6580997f, 128.0f};
  __shared__ float ebuf[60][64];
  int tid = threadIdx.x;
  int p = blockIdx.x * 64 + tid;
  #pragma unroll
  for (int c = 0; c < 3; c++) {
    float pos = mp[p * 3 + c];
    #pragma unroll
    for (int i = 0; i < 10; i++) {
      float ang = (TWO_PI_F * pos) * freqs[i];
      ebuf[c * 20 + i][tid]      = sinf(ang);
      ebuf[c * 20 + 10 + i][tid] = cosf(ang);
    }
  }
  float h[64];
  #pragma unroll
  for (int j = 0; j < 64; j++) h[j] = 0.0f;
  for (int k = 0; k < 60; k++) {
    float ek = ebuf[k][tid];
    const float* wr = W_in + k * 64;
    #pragma unroll
    for (int j = 0; j < 64; j++) h[j] = fmaf(ek, wr[j], h[j]);
  }
  float* o = encpart + (size_t)p * 64;
  #pragma unroll
  for (int j = 0; j < 64; j++) o[j] = h[j];
}

// ------- prep: zpart[b][64], W^T A-fragments (bf16), zero stripCntSeg -------
__global__ __launch_bounds__(256) void prep_kernel(const float* __restrict__ z,
                                                   const float* __restrict__ W_in,
                                                   const float* __restrict__ W_layers,
                                                   float* __restrict__ zpart,
                                                   unsigned short* __restrict__ Wfrag,
                                                   int* __restrict__ stripCntSeg) {
  int idx = blockIdx.x * 256 + threadIdx.x;     // 0..4095
  stripCntSeg[idx] = 0;                          // Bn*8*16 = 4096 ints
  if (idx < 2048) {
    int b = idx >> 6, j = idx & 63;
    float s = 0.0f;
    #pragma unroll
    for (int k = 0; k < 10; k++) s = fmaf(z[b * 10 + k], W_in[(60 + k) * 64 + j], s);
    zpart[b * 64 + j] = s;
  } else {
    int t2 = idx - 2048;
    int L = t2 >> 9, m = (t2 >> 7) & 3, s = (t2 >> 6) & 1, lane = t2 & 63;
    #pragma unroll
    for (int i = 0; i < 8; i++) {
      int k = s * 32 + ((lane >> 4) * 8) + i;
      int j = m * 16 + (lane & 15);
      Wfrag[(size_t)t2 * 8 + i] = f2bf(W_layers[L * 4096 + k * 64 + j]);
    }
  }
}

// ---- D->B regroup: fixed lane-group gather (verified rounds 4-17) ----
__device__ __forceinline__ void regroup(const v4f* acc, v8s* Bf,
                                        int srcA, int srcB, bool hi) {
  union U4 { int u[4]; v8s v; };
  int pk[4][2];
  #pragma unroll
  for (int m = 0; m < 4; m++) {
    pk[m][0] = cvt_pk_bf16(acc[m][0], acc[m][1]);
    pk[m][1] = cvt_pk_bf16(acc[m][2], acc[m][3]);
  }
  #pragma unroll
  for (int s = 0; s < 2; s++) {
    int t00 = __builtin_amdgcn_ds_bpermute(srcA, pk[2 * s][0]);
    int t01 = __builtin_amdgcn_ds_bpermute(srcA, pk[2 * s + 1][0]);
    int t10 = __builtin_amdgcn_ds_bpermute(srcA, pk[2 * s][1]);
    int t11 = __builtin_amdgcn_ds_bpermute(srcA, pk[2 * s + 1][1]);
    int t20 = __builtin_amdgcn_ds_bpermute(srcB, pk[2 * s][0]);
    int t21 = __builtin_amdgcn_ds_bpermute(srcB, pk[2 * s + 1][0]);
    int t30 = __builtin_amdgcn_ds_bpermute(srcB, pk[2 * s][1]);
    int t31 = __builtin_amdgcn_ds_bpermute(srcB, pk[2 * s + 1][1]);
    U4 u;
    u.u[0] = hi ? t01 : t00;
    u.u[1] = hi ? t11 : t10;
    u.u[2] = hi ? t21 : t20;
    u.u[3] = hi ? t31 : t30;
    Bf[s] = u.v;
  }
}

// ------- all-register MFMA MLP, 32 points/wave (round-16 verified body) -----
__global__ __launch_bounds__(256) void mlp_mfma32_kernel(
    const float* __restrict__ encpart, const float* __restrict__ zpart,
    const unsigned short* __restrict__ Wfrag,
    const float* __restrict__ W_out1, const float* __restrict__ W_out2,
    const float* __restrict__ mp, const float* __restrict__ orient,
    const float* __restrict__ amp, const float* __restrict__ ampvar,
    float4* __restrict__ rec, int* __restrict__ stripCntSeg,
    float* __restrict__ out_fp, float* __restrict__ out_disp) {
  __shared__ int h16[16];
  int tid = threadIdx.x;
  int lane = tid & 63;
  int wave = tid >> 6;
  int wid = blockIdx.x * 4 + wave;            // 0..16383
  int b = __builtin_amdgcn_readfirstlane(wid >> 9);
  int pbase = (wid & 511) * 32;
  int g = lane >> 4;
  int p0 = pbase + (lane & 15);
  int p1 = p0 + 16;

  if (tid < 16) h16[tid] = 0;
  __syncthreads();

  union U4 { int u[4]; v8s v; };

  v8s Bf0[2], Bf1[2];
  #pragma unroll
  for (int s = 0; s < 2; s++) {
    int k0 = s * 32 + g * 8;
    const float4* z4 = (const float4*)(zpart + b * 64 + k0);
    float4 z0 = z4[0], z1 = z4[1];
    {
      const float4* e4 = (const float4*)(encpart + (size_t)p0 * 64 + k0);
      float4 e0 = e4[0], e1 = e4[1];
      U4 u;
      u.u[0] = cvt_pk_bf16(e0.x + z0.x, e0.y + z0.y);
      u.u[1] = cvt_pk_bf16(e0.z + z0.z, e0.w + z0.w);
      u.u[2] = cvt_pk_bf16(e1.x + z1.x, e1.y + z1.y);
      u.u[3] = cvt_pk_bf16(e1.z + z1.z, e1.w + z1.w);
      Bf0[s] = u.v;
    }
    {
      const float4* e4 = (const float4*)(encpart + (size_t)p1 * 64 + k0);
      float4 e0 = e4[0], e1 = e4[1];
      U4 u;
      u.u[0] = cvt_pk_bf16(e0.x + z0.x, e0.y + z0.y);
      u.u[1] = cvt_pk_bf16(e0.z + z0.z, e0.w + z0.w);
      u.u[2] = cvt_pk_bf16(e1.x + z1.x, e1.y + z1.y);
      u.u[3] = cvt_pk_bf16(e1.z + z1.z, e1.w + z1.w);
      Bf1[s] = u.v;
    }
  }

  int srcA = ((((lane >> 4) & 1) * 32) + (lane & 15)) << 2;
  int srcB = srcA + 64;
  bool hi = (lane >> 5) & 1;

  const v8s* WfragV = (const v8s*)Wfrag;
  v4f acc0[4], acc1[4];

  #pragma unroll 1
  for (int L = 0; L < 4; L++) {
    v8s Af[4][2];
    #pragma unroll
    for (int m = 0; m < 4; m++)
      #pragma unroll
      for (int s = 0; s < 2; s++)
        Af[m][s] = WfragV[(size_t)(((L * 4 + m) * 2 + s) * 64) + lane];

    #pragma unroll
    for (int m = 0; m < 4; m++) {
      acc0[m] = (v4f){0.f, 0.f, 0.f, 0.f};
      acc1[m] = (v4f){0.f, 0.f, 0.f, 0.f};
    }
    #pragma unroll
    for (int s = 0; s < 2; s++) {
      #pragma unroll
      for (int m = 0; m < 4; m++)
        acc0[m] = __builtin_amdgcn_mfma_f32_16x16x32_bf16(Af[m][s], Bf0[s], acc0[m], 0, 0, 0);
      #pragma unroll
      for (int m = 0; m < 4; m++)
        acc1[m] = __builtin_amdgcn_mfma_f32_16x16x32_bf16(Af[m][s], Bf1[s], acc1[m], 0, 0, 0);
    }

    #pragma unroll
    for (int m = 0; m < 4; m++)
      #pragma unroll
      for (int r = 0; r < 4; r++) {
        acc0[m][r] = elu_f(acc0[m][r]);
        acc1[m][r] = elu_f(acc1[m][r]);
      }

    if (L < 3) {
      regroup(acc0, Bf0, srcA, srcB, hi);
      regroup(acc1, Bf1, srcA, srcB, hi);
    }
  }

  float o00 = 0.f, o01 = 0.f, o02 = 0.f;
  float o10 = 0.f, o11 = 0.f, o12 = 0.f;
  #pragma unroll
  for (int m = 0; m < 4; m++) {
    int jb = m * 16 + g * 4;
    const float4* w4 = (const float4*)(W_out1 + jb * 3);
    float4 wa = w4[0], wb = w4[1], wc = w4[2];
    o00 += acc0[m][0] * wa.x + acc0[m][1] * wa.w + acc0[m][2] * wb.z + acc0[m][3] * wc.y;
    o01 += acc0[m][0] * wa.y + acc0[m][1] * wb.x + acc0[m][2] * wb.w + acc0[m][3] * wc.z;
    o02 += acc0[m][0] * wa.z + acc0[m][1] * wb.y + acc0[m][2] * wc.x + acc0[m][3] * wc.w;
    o10 += acc1[m][0] * wa.x + acc1[m][1] * wa.w + acc1[m][2] * wb.z + acc1[m][3] * wc.y;
    o11 += acc1[m][0] * wa.y + acc1[m][1] * wb.x + acc1[m][2] * wb.w + acc1[m][3] * wc.z;
    o12 += acc1[m][0] * wa.z + acc1[m][1] * wb.y + acc1[m][2] * wc.x + acc1[m][3] * wc.w;
  }
  o00 += __shfl_xor(o00, 16, 64); o00 += __shfl_xor(o00, 32, 64);
  o01 += __shfl_xor(o01, 16, 64); o01 += __shfl_xor(o01, 32, 64);
  o02 += __shfl_xor(o02, 16, 64); o02 += __shfl_xor(o02, 32, 64);
  o10 += __shfl_xor(o10, 16, 64); o10 += __shfl_xor(o10, 32, 64);
  o11 += __shfl_xor(o11, 16, 64); o11 += __shfl_xor(o11, 32, 64);
  o12 += __shfl_xor(o12, 16, 64); o12 += __shfl_xor(o12, 32, 64);

  o00 = elu_f(o00); o01 = elu_f(o01); o02 = elu_f(o02);
  o10 = elu_f(o10); o11 = elu_f(o11); o12 = elu_f(o12);

  float W0 = W_out2[0], W1 = W_out2[1], W2 = W_out2[2];
  float W3 = W_out2[3], W4 = W_out2[4], W5 = W_out2[5];
  float W6 = W_out2[6], W7 = W_out2[7], W8 = W_out2[8];

  float d00 = o00 * W0 + o01 * W3 + o02 * W6;
  float d01 = o00 * W1 + o01 * W4 + o02 * W7;
  float d02 = o00 * W2 + o01 * W5 + o02 * W8;
  float d10 = o10 * W0 + o11 * W3 + o12 * W6;
  float d11 = o10 * W1 + o11 * W4 + o12 * W7;
  float d12 = o10 * W2 + o11 * W5 + o12 * W8;

  float m00 = mp[p0 * 3 + 0], m01 = mp[p0 * 3 + 1], m02 = mp[p0 * 3 + 2];
  float m10 = mp[p1 * 3 + 0], m11 = mp[p1 * 3 + 1], m12 = mp[p1 * 3 + 2];
  float f00 = m00 + d00, f01 = m01 + d01, f02 = m02 + d02;
  float f10 = m10 + d10, f11 = m11 + d11, f12 = m12 + d12;

  size_t ob0 = ((size_t)b * Pn + p0) * 3;
  size_t ob1 = ((size_t)b * Pn + p1) * 3;
  if (g == 2) {
    out_disp[ob0 + 0] = d00; out_disp[ob0 + 1] = d01; out_disp[ob0 + 2] = d02;
    out_fp[ob0 + 0] = f00; out_fp[ob0 + 1] = f01; out_fp[ob0 + 2] = f02;
  }
  if (g == 3) {
    out_disp[ob1 + 0] = d10; out_disp[ob1 + 1] = d11; out_disp[ob1 + 2] = d12;
    out_fp[ob1 + 0] = f10; out_fp[ob1 + 1] = f11; out_fp[ob1 + 2] = f12;
  }

  const float* R = orient + b * 9;
  float px0 = R[0] * f00 + R[1] * f01 + R[2] * f02;
  float py0 = R[3] * f00 + R[4] * f01 + R[5] * f02;
  float px1 = R[0] * f10 + R[1] * f11 + R[2] * f12;
  float py1 = R[3] * f10 + R[4] * f11 + R[5] * f12;

  float a00 = ampvar[p0], a01 = ampvar[Pn + p0];
  float mx0 = fmaxf(a00, a01);
  float e00 = __expf(a00 - mx0), e01 = __expf(a01 - mx0);
  float inv0 = 1.0f / (e00 + e01);
  float w00a = amp[p0] * e00 * inv0;
  float w01a = amp[Pn + p0] * e01 * inv0;
  float a10 = ampvar[p1], a11 = ampvar[Pn + p1];
  float mx1 = fmaxf(a10, a11);
  float e10 = __expf(a10 - mx1), e11 = __expf(a11 - mx1);
  float inv1 = 1.0f / (e10 + e11);
  float w10a = amp[p1] * e10 * inv1;
  float w11a = amp[Pn + p1] * e11 * inv1;

  float pxp0 = fminf(fmaxf((px0 + 0.5f) * 256.0f, 0.0f), 254.999f);
  float pyp0 = fminf(fmaxf((py0 + 0.5f) * 256.0f, 0.0f), 254.999f);
  float pxp1 = fminf(fmaxf((px1 + 0.5f) * 256.0f, 0.0f), 254.999f);
  float pyp1 = fminf(fmaxf((py1 + 0.5f) * 256.0f, 0.0f), 254.999f);

  if (g == 0) {
    atomicAdd(&h16[((int)pyp0) >> 4], 1);
    rec[(size_t)b * Pn + p0] = make_float4(pxp0, pyp0, w00a, w01a);
  }
  if (g == 1) {
    atomicAdd(&h16[((int)pyp1) >> 4], 1);
    rec[(size_t)b * Pn + p1] = make_float4(pxp1, pyp1, w10a, w11a);
  }
  __syncthreads();
  int bblk = __builtin_amdgcn_readfirstlane(blockIdx.x >> 7);
  int seg  = __builtin_amdgcn_readfirstlane((blockIdx.x & 127) >> 4);
  if (tid < 16 && h16[tid] != 0)
    atomicAdd(&stripCntSeg[(bblk * 8 + seg) * 16 + tid], h16[tid]);
}

// -------- scatter16: per-(b,seg), group records by y-strip (LDS cursors) ----
__global__ __launch_bounds__(256) void scatter16_kernel(const float4* __restrict__ rec,
                                                        const int* __restrict__ stripCntSeg,
                                                        float4* __restrict__ sorted) {
  __shared__ int tot[16], start[16], cur[16];
  int blk = blockIdx.x;
  int b = blk >> 3, seg = blk & 7;
  int tid = threadIdx.x;
  int myoff = 0;
  if (tid < 16) {
    int acc = 0, so = 0;
    #pragma unroll
    for (int s = 0; s < 8; s++) {
      int c = stripCntSeg[(b * 8 + s) * 16 + tid];
      if (s < seg) so += c;
      acc += c;
    }
    tot[tid] = acc; myoff = so;
  }
  __syncthreads();
  if (tid == 0) { int a = 0; for (int i = 0; i < 16; i++) { start[i] = a; a += tot[i]; } }
  __syncthreads();
  if (tid < 16) cur[tid] = start[tid] + myoff;
  __syncthreads();
  int base = seg * 2048;
  for (int i = base + tid; i < base + 2048; i += 256) {
    float4 r = rec[(size_t)b * Pn + i];
    int strip = ((int)r.y) >> 4;
    int slot = atomicAdd(&cur[strip], 1);
    sorted[(size_t)b * Pn + slot] = r;
  }
}

// ------- F1 (fused splat + row FFT): block = (b, 8-row chunk), 1024 blocks.
// Strip-sorted contiguous reads (strips [(8c-1)>>4, (8c+7)>>4]); native int
// LDS atomics (fixed-point x2048) aliased onto the complex buffer; per-wave
// fence-only float2 FFTs (2/wave); Hermitian unpack; transposed write [kx][y].
__global__ __launch_bounds__(256) void splat_fft_rows_T(const float4* __restrict__ sorted,
                                                        const int* __restrict__ stripCntSeg,
                                                        float2* __restrict__ ws1) {
  __shared__ float2 scx[8][257];
  __shared__ float2 tw[128];
  __shared__ int tot[16], start[16];
  int tid = threadIdx.x;
  int lane = tid & 63, wave = tid >> 6;
  int blk = blockIdx.x;
  int chunk = blk & 31, b = blk >> 5;
  for (int t = tid; t < 128; t += 256) {
    float ang = -TWO_PI_F * (float)t / 256.0f;
    tw[t] = make_float2(cosf(ang), sinf(ang));
  }
  if (tid < 16) {
    int acc = 0;
    #pragma unroll
    for (int s = 0; s < 8; s++) acc += stripCntSeg[(b * 8 + s) * 16 + tid];
    tot[tid] = acc;
  }
  float2* fc = &scx[0][0];
  int* ip = (int*)fc;
  for (int j = tid; j < 8 * 257; j += 256) fc[j] = make_float2(0.f, 0.f);
  __syncthreads();
  if (tid == 0) { int a = 0; for (int i = 0; i < 16; i++) { start[i] = a; a += tot[i]; } }
  __syncthreads();

  int ybase = chunk * 8;
  int loS = (chunk > 0) ? ((ybase - 1) >> 4) : 0;
  int hiS = (ybase + 7) >> 4;
  int lo = start[loS];
  int hi = start[hiS] + tot[hiS];
  const float4* rb = sorted + (size_t)b * Pn;
  for (int i = lo + tid; i < hi; i += 256) {
    float4 r = rb[i];
    int y0 = (int)r.y;
    int d = y0 - ybase;
    if (d >= -1 && d <= 7) {
      int x0 = (int)r.x;
      int x1 = x0 + 1;                       // x0 <= 254 by clamp
      float fx = r.x - (float)x0, fy = r.y - (float)y0;
      float w00 = (1.f - fx) * (1.f - fy), w10 = fx * (1.f - fy);
      float w01 = (1.f - fx) * fy,         w11 = fx * fy;
      if (d >= 0) {
        int e0 = (d * 257 + x0) * 2, e1 = (d * 257 + x1) * 2;
        atomicAdd(&ip[e0],     __float2int_rn(r.z * w00 * SPLAT_SCALE));
        atomicAdd(&ip[e0 + 1], __float2int_rn(r.w * w00 * SPLAT_SCALE));
        atomicAdd(&ip[e1],     __float2int_rn(r.z * w10 * SPLAT_SCALE));
        atomicAdd(&ip[e1 + 1], __float2int_rn(r.w * w10 * SPLAT_SCALE));
      }
      if (d <= 6) {
        int e0 = ((d + 1) * 257 + x0) * 2, e1 = ((d + 1) * 257 + x1) * 2;
        atomicAdd(&ip[e0],     __float2int_rn(r.z * w01 * SPLAT_SCALE));
        atomicAdd(&ip[e0 + 1], __float2int_rn(r.w * w01 * SPLAT_SCALE));
        atomicAdd(&ip[e1],     __float2int_rn(r.z * w11 * SPLAT_SCALE));
        atomicAdd(&ip[e1 + 1], __float2int_rn(r.w * w11 * SPLAT_SCALE));
      }
    }
  }
  __syncthreads();
  for (int j = tid; j < 8 * 257; j += 256) {
    int2 v = ((const int2*)ip)[j];
    fc[j] = make_float2((float)v.x * SPLAT_INV, (float)v.y * SPLAT_INV);
  }
  __syncthreads();

  // 2 wave-private FFTs per wave, fence-only, complex layout
  #pragma unroll 1
  for (int rnd = 0; rnd < 2; rnd++) {
    int row = wave * 2 + rnd;
    fft256_c(&scx[row][0], tw, lane, false);
  }
  __syncthreads();
  // unpack: Z0 = (Z(k)+conj(Z(m)))/2, Z1 = -i/2 (Z(k)-conj(Z(m))), m=(256-k)&255
  #pragma unroll 1
  for (int ko = 0; ko < 5; ko++) {
    int kx = ko * 32 + (tid >> 3);
    int ysub = tid & 7;
    if (kx < KXD) {
      int m = (256 - kx) & 255;
      float2 zv = scx[ysub][kx];
      float2 mv = scx[ysub][m];
      float z0r = 0.5f * (zv.x + mv.x), z0i = 0.5f * (zv.y - mv.y);
      float z1r = 0.5f * (zv.y + mv.y), z1i = 0.5f * (mv.x - zv.x);
      size_t y = (size_t)(chunk * 8 + ysub);
      ws1[((size_t)(b * 2 + 0) * KXD + kx) * 256 + y] = make_float2(z0r, z0i);
      ws1[((size_t)(b * 2 + 1) * KXD + kx) * 256 + y] = make_float2(z1r, z1i);
    }
  }
}

// ------- F2: per kx line: fwd y-FFT both classes, filter-combine, phase_y,
//         inv y-FFT; write line kx AND conjugate mirror, transposed [y][kx] --
__global__ __launch_bounds__(256) void fft_mid_T(const float2* __restrict__ ws1,
                                                 float2* __restrict__ A2,
                                                 const float* __restrict__ shift,
                                                 const float* __restrict__ Aarr,
                                                 const float* __restrict__ Bparr) {
  __shared__ float2 scx[4][257], wcx[4][257];
  __shared__ float2 tw[128];
  int tid = threadIdx.x;
  int lane = tid & 63, wave = tid >> 6;
  int blk = blockIdx.x;
  int b = blk / 33, c33 = blk % 33;
  int kx = c33 * 4 + wave;                   // 0..131
  for (int t = tid; t < 128; t += 256) {
    float ang = -TWO_PI_F * (float)t / 256.0f;
    tw[t] = make_float2(cosf(ang), sinf(ang));
  }
  __syncthreads();
  float A0 = Aarr[0], A1 = Aarr[1], B0 = Bparr[0], B1 = Bparr[1];
  float sy = shift[b * 2 + 1];
  const float2* r0 = ws1 + ((size_t)(b * 2 + 0) * KXD + kx) * 256;
  const float2* r1 = ws1 + ((size_t)(b * 2 + 1) * KXD + kx) * 256;
  #pragma unroll
  for (int q = 0; q < 4; q++) {
    int i = lane + q * 64;
    scx[wave][i] = r0[i];
    wcx[wave][i] = r1[i];
  }
  wave_lds_fence();
  fft256_c(&scx[wave][0], tw, lane, false);
  fft256_c(&wcx[wave][0], tw, lane, false);
  float rx = (kx <= 128) ? (float)kx : (float)(256 - kx);
  #pragma unroll
  for (int q = 0; q < 4; q++) {
    int ky = lane + q * 64;
    float ry = (ky <= 128) ? (float)ky : (float)(256 - ky);
    float R = sqrtf(rx * rx + ry * ry);
    float FF0 = A0 * A0 * __expf(-B0 * B0 * R);
    float FF1 = A1 * A1 * __expf(-B1 * B1 * R);
    float2 sv = scx[wave][ky];
    float2 wv = wcx[wave][ky];
    float Gr = FF0 * sv.x + FF1 * wv.x;
    float Gi = FF0 * sv.y + FF1 * wv.y;
    float fk = (float)((ky < 128) ? ky : ky - 256) / 256.0f;
    float th = -TWO_PI_F * fk * sy;
    float cc = __cosf(th), ss = __sinf(th);
    scx[wave][ky] = make_float2(Gr * cc - Gi * ss, Gr * ss + Gi * cc);
  }
  wave_lds_fence();
  fft256_c(&scx[wave][0], tw, lane, true);
  __syncthreads();   // cross-wave transposed write below
  const float inv = 1.0f / 256.0f;
  int kx0 = c33 * 4;
  #pragma unroll 1
  for (int yo = 0; yo < 4; yo++) {
    int ksub = tid & 3;
    int y = yo * 64 + (tid >> 2);
    int kxw = kx0 + ksub;
    float2 v = scx[ksub][y];
    float vr = v.x * inv, vi = v.y * inv;
    if (kxw <= 128)
      A2[(size_t)b * 65536 + (size_t)y * 256 + kxw] = make_float2(vr, vi);
    if (kxw >= 1 && kxw <= 127)
      A2[(size_t)b * 65536 + (size_t)y * 256 + (256 - kxw)] = make_float2(vr, -vi);
  }
}

// ------- F3: packed pair inverse x-FFT (Hermitian projection via shuffles) --
__global__ __launch_bounds__(256) void fft_final_pk(const float2* __restrict__ A2t,
                                                    const float* __restrict__ shift,
                                                    float* __restrict__ out_imgs) {
  __shared__ float2 X[4][257];
  __shared__ float2 tw[128];
  int tid = threadIdx.x;
  int lane = tid & 63, wave = tid >> 6;
  int blk = blockIdx.x;
  int b = blk >> 5, grp = blk & 31;
  int y0 = grp * 8 + wave * 2;
  int y1 = y0 + 1;
  for (int t = tid; t < 128; t += 256) {
    float ang = -TWO_PI_F * (float)t / 256.0f;
    tw[t] = make_float2(cosf(ang), sinf(ang));
  }
  __syncthreads();   // twiddles written by waves 0-1, read by all
  float sx = shift[b * 2 + 0];
  const float2* row0 = A2t + (size_t)b * 65536 + (size_t)y0 * 256;
  const float2* row1 = A2t + (size_t)b * 65536 + (size_t)y1 * 256;
  float g0r[4], g0i[4], g1r[4], g1i[4];
  #pragma unroll
  for (int q = 0; q < 4; q++) {
    int k = lane + q * 64;
    float2 v0 = row0[k], v1 = row1[k];
    float fk = (float)((k < 128) ? k : k - 256) / 256.0f;
    float th = -TWO_PI_F * fk * sx;
    float c = __cosf(th), s = __sinf(th);
    g0r[q] = v0.x * c - v0.y * s;  g0i[q] = v0.x * s + v0.y * c;
    g1r[q] = v1.x * c - v1.y * s;  g1i[q] = v1.x * s + v1.y * c;
  }
  int src = (64 - lane) & 63;
  float s0r[4], s0i[4], s1r[4], s1i[4];
  #pragma unroll
  for (int j = 0; j < 4; j++) {
    s0r[j] = __shfl(g0r[j], src, 64);  s0i[j] = __shfl(g0i[j], src, 64);
    s1r[j] = __shfl(g1r[j], src, 64);  s1i[j] = __shfl(g1i[j], src, 64);
  }
  bool l0 = (lane == 0);
  #pragma unroll
  for (int q = 0; q < 4; q++) {
    const int qa = 3 - q;          // lane >= 1
    const int qb = (4 - q) & 3;    // lane == 0
    float m0r = l0 ? s0r[qb] : s0r[qa];
    float m0i = l0 ? s0i[qb] : s0i[qa];
    float m1r = l0 ? s1r[qb] : s1r[qa];
    float m1i = l0 ? s1i[qb] : s1i[qa];
    float h0r = 0.5f * (g0r[q] + m0r), h0i = 0.5f * (g0i[q] - m0i);
    float h1r = 0.5f * (g1r[q] + m1r), h1i = 0.5f * (g1i[q] - m1i);
    int k = lane + q * 64;
    X[wave][k] = make_float2(h0r - h1i, h0i + h1r);   // pack: hg0 + i*hg1
  }
  wave_lds_fence();
  fft256_c(&X[wave][0], tw, lane, true);
  const float inv = 1.0f / 256.0f;
  float* o0 = out_imgs + (size_t)b * 65536 + (size_t)y0 * 256;
  float* o1 = out_imgs + (size_t)b * 65536 + (size_t)y1 * 256;
  #pragma unroll
  for (int q = 0; q < 4; q++) {
    int x = lane + q * 64;
    float2 v = X[wave][x];
    o0[x] = v.x * inv;
    o1[x] = v.y * inv;
  }
}

// ---------------- launch ----------------
extern "C" void kernel_launch(void* const* d_in, const int* in_sizes, int n_in,
                              void* d_out, int out_size, void* d_ws, size_t ws_size,
                              hipStream_t stream) {
  (void)in_sizes; (void)n_in; (void)out_size; (void)ws_size;
  const float* z       = (const float*)d_in[0];
  const float* orient  = (const float*)d_in[1];
  const float* shift   = (const float*)d_in[2];
  const float* mp      = (const float*)d_in[3];
  const float* W_in    = (const float*)d_in[4];
  const float* W_layers= (const float*)d_in[5];
  const float* W_out1  = (const float*)d_in[6];
  const float* W_out2  = (const float*)d_in[7];
  const float* amp     = (const float*)d_in[8];
  const float* ampvar  = (const float*)d_in[9];
  const float* Aarr    = (const float*)d_in[10];
  const float* Bparr   = (const float*)d_in[11];

  char* ws0 = (char*)d_ws;
  // Region0 (sequential lifetimes): encpart(4MB, enc->mlp) -> A2(16.8MB, F2->F3)
  float*  encpart = (float*)ws0;
  float2* A2      = (float2*)ws0;
  // RegionB at +19MiB; all buffers disjoint.
  char* wsB = ws0 + 19922944;
  float2* ws1     = (float2*)wsB;                         // 17,301,504 B (F1->F2)
  float4* rec     = (float4*)(wsB + 17301504);            // 8 MiB (mlp->scatter)
  float4* sorted  = (float4*)(wsB + 25690112);            // 8 MiB (scatter->F1)
  float*  zpart   = (float*)(wsB + 34078720);             // 8 KB
  unsigned short* Wfrag = (unsigned short*)(wsB + 34078720 + 8192);  // 32 KB
  int* stripCntSeg = (int*)(wsB + 34078720 + 40960);      // 16 KB

  float* out      = (float*)d_out;
  float* out_imgs = out;                               // [B][S][S]
  float* out_fp   = out + (size_t)Bn * Sn * Sn;        // [B][P][3]
  float* out_disp = out_fp + (size_t)Bn * Pn * 3;      // [B][P][3]

  enc_kernel<<<Pn / 64, 64, 0, stream>>>(mp, W_in, encpart);
  prep_kernel<<<16, 256, 0, stream>>>(z, W_in, W_layers, zpart, Wfrag, stripCntSeg);
  mlp_mfma32_kernel<<<(Bn * Pn / 32) / 4, 256, 0, stream>>>(
      encpart, zpart, Wfrag, W_out1, W_out2, mp, orient, amp, ampvar,
      rec, stripCntSeg, out_fp, out_disp);
  scatter16_kernel<<<Bn * 8, 256, 0, stream>>>(rec, stripCntSeg, sorted);
  splat_fft_rows_T<<<Bn * 32, 256, 0, stream>>>(sorted, stripCntSeg, ws1);
  fft_mid_T<<<Bn * 33, 256, 0, stream>>>(ws1, A2, shift, Aarr, Bparr);
  fft_final_pk<<<Bn * 32, 256, 0, stream>>>(A2, shift, out_imgs);
}

// Round 19
// 173.472 us; speedup vs baseline: 1.0600x; 1.0001x over previous
//
#include <hip/hip_runtime.h>
#include <math.h>

static constexpr int Bn = 32, Pn = 16384, Cn = 2, Sn = 256;
static constexpr int KXD = 132;   // stored kx lines in ws1 (0..131; >=129 unused)

#define TWO_PI_F 6.28318530717958647692f
#define SPLAT_SCALE 2048.0f
#define SPLAT_INV   (1.0f / 2048.0f)

typedef float v4f __attribute__((ext_vector_type(4)));
typedef short v8s __attribute__((ext_vector_type(8)));

__device__ __forceinline__ float elu_f(float x) {
  return x > 0.0f ? x : (__expf(x) - 1.0f);
}

__device__ __forceinline__ unsigned short f2bf(float x) {
  unsigned int u = __float_as_uint(x);
  u = u + 0x7FFFu + ((u >> 16) & 1u);
  return (unsigned short)(u >> 16);
}

__device__ __forceinline__ int cvt_pk_bf16(float lo, float hi) {
  int r;
  asm("v_cvt_pk_bf16_f32 %0, %1, %2" : "=v"(r) : "v"(lo), "v"(hi));
  return r;
}

// Compiler-only fence: no instructions; forbids reordering/forwarding of LDS
// accesses across it (HW processes a wave's DS ops in order).
__device__ __forceinline__ void wave_lds_fence() {
  __builtin_amdgcn_sched_barrier(0);
  asm volatile("" ::: "memory");
}

// ---- 256-pt FFT on a WAVE-PRIVATE LDS row (interleaved complex float2),
// fence-only. Validated rounds 14-18. ----------------------------------------
__device__ __forceinline__ void fft256_c(float2* X, const float2* tw,
                                         int lane, bool inverse) {
  #pragma unroll
  for (int q = 0; q < 4; q++) {
    int t = lane + q * 64;
    int r = (int)(__brev((unsigned)t) >> 24);
    if (t < r) { float2 a = X[t]; X[t] = X[r]; X[r] = a; }
  }
  wave_lds_fence();
  #pragma unroll
  for (int s = 1; s <= 8; s++) {
    int half = 1 << (s - 1);
    #pragma unroll
    for (int q = 0; q < 2; q++) {
      int bf = lane + q * 64;
      int j = bf & (half - 1);
      int grp = bf >> (s - 1);
      int i0 = (grp << s) + j;
      int i1 = i0 + half;
      float2 w = tw[j << (8 - s)];
      float wi = inverse ? -w.y : w.y;
      float2 x1 = X[i1];
      float tr = fmaf(x1.x, w.x, -x1.y * wi);
      float ti = fmaf(x1.x, wi,  x1.y * w.x);
      float2 x0 = X[i0];
      X[i0] = make_float2(x0.x + tr, x0.y + ti);
      X[i1] = make_float2(x0.x - tr, x0.y - ti);
    }
    wave_lds_fence();
  }
}

// ---- PAIRED 256-pt FFT: two INDEPENDENT wave-private rows interleaved in
// one stage loop (single fence per stage) -> 2x independent LDS work between
// fences, hiding LDS latency without extra occupancy. Same math as fft256_c.
__device__ __forceinline__ void fft256_c2(float2* X, float2* Y, const float2* tw,
                                          int lane, bool inverse) {
  #pragma unroll
  for (int q = 0; q < 4; q++) {
    int t = lane + q * 64;
    int r = (int)(__brev((unsigned)t) >> 24);
    if (t < r) {
      float2 a = X[t]; X[t] = X[r]; X[r] = a;
      float2 b = Y[t]; Y[t] = Y[r]; Y[r] = b;
    }
  }
  wave_lds_fence();
  #pragma unroll
  for (int s = 1; s <= 8; s++) {
    int half = 1 << (s - 1);
    #pragma unroll
    for (int q = 0; q < 2; q++) {
      int bf = lane + q * 64;
      int j = bf & (half - 1);
      int grp = bf >> (s - 1);
      int i0 = (grp << s) + j;
      int i1 = i0 + half;
      float2 w = tw[j << (8 - s)];
      float wi = inverse ? -w.y : w.y;
      float2 x1 = X[i1];
      float2 y1 = Y[i1];
      float xtr = fmaf(x1.x, w.x, -x1.y * wi);
      float xti = fmaf(x1.x, wi,  x1.y * w.x);
      float ytr = fmaf(y1.x, w.x, -y1.y * wi);
      float yti = fmaf(y1.x, wi,  y1.y * w.x);
      float2 x0 = X[i0];
      float2 y0 = Y[i0];
      X[i0] = make_float2(x0.x + xtr, x0.y + xti);
      X[i1] = make_float2(x0.x - xtr, x0.y - xti);
      Y[i0] = make_float2(y0.x + ytr, y0.y + yti);
      Y[i1] = make_float2(y0.x - ytr, y0.y - yti);
    }
    wave_lds_fence();
  }
}

// ---------------- enc precompute: encpart[p][64] = enc(p) @ W_in[0:60] ------
__global__ __launch_bounds__(64) void enc_kernel(const float* __restrict__ mp,
                                                 const float* __restrict__ W_in,
                                                 float* __restrict__ encpart) {
  const float freqs[10] = {1.0f, 1.71448797f, 2.93946898f, 5.03968420f,
                           8.64050360f, 14.8140558f, 25.3984847f,
                           43.5454520f, 74.6580997f, 128.0f};
  __shared__ float ebuf[60][64];
  int tid = threadIdx.x;
  int p = blockIdx.x * 64 + tid;
  #pragma unroll
  for (int c = 0; c < 3; c++) {
    float pos = mp[p * 3 + c];
    #pragma unroll
    for (int i = 0; i < 10; i++) {
      float ang = (TWO_PI_F * pos) * freqs[i];
      ebuf[c * 20 + i][tid]      = sinf(ang);
      ebuf[c * 20 + 10 + i][tid] = cosf(ang);
    }
  }
  float h[64];
  #pragma unroll
  for (int j = 0; j < 64; j++) h[j] = 0.0f;
  for (int k = 0; k < 60; k++) {
    float ek = ebuf[k][tid];
    const float* wr = W_in + k * 64;
    #pragma unroll
    for (int j = 0; j < 64; j++) h[j] = fmaf(ek, wr[j], h[j]);
  }
  float* o = encpart + (size_t)p * 64;
  #pragma unroll
  for (int j = 0; j < 64; j++) o[j] = h[j];
}

// ------- prep: zpart[b][64], W^T A-fragments (bf16), zero stripCntSeg -------
__global__ __launch_bounds__(256) void prep_kernel(const float* __restrict__ z,
                                                   const float* __restrict__ W_in,
                                                   const float* __restrict__ W_layers,
                                                   float* __restrict__ zpart,
                                                   unsigned short* __restrict__ Wfrag,
                                                   int* __restrict__ stripCntSeg) {
  int idx = blockIdx.x * 256 + threadIdx.x;     // 0..4095
  stripCntSeg[idx] = 0;                          // Bn*8*16 = 4096 ints
  if (idx < 2048) {
    int b = idx >> 6, j = idx & 63;
    float s = 0.0f;
    #pragma unroll
    for (int k = 0; k < 10; k++) s = fmaf(z[b * 10 + k], W_in[(60 + k) * 64 + j], s);
    zpart[b * 64 + j] = s;
  } else {
    int t2 = idx - 2048;
    int L = t2 >> 9, m = (t2 >> 7) & 3, s = (t2 >> 6) & 1, lane = t2 & 63;
    #pragma unroll
    for (int i = 0; i < 8; i++) {
      int k = s * 32 + ((lane >> 4) * 8) + i;
      int j = m * 16 + (lane & 15);
      Wfrag[(size_t)t2 * 8 + i] = f2bf(W_layers[L * 4096 + k * 64 + j]);
    }
  }
}

// ---- D->B regroup: fixed lane-group gather (verified rounds 4-18) ----
__device__ __forceinline__ void regroup(const v4f* acc, v8s* Bf,
                                        int srcA, int srcB, bool hi) {
  union U4 { int u[4]; v8s v; };
  int pk[4][2];
  #pragma unroll
  for (int m = 0; m < 4; m++) {
    pk[m][0] = cvt_pk_bf16(acc[m][0], acc[m][1]);
    pk[m][1] = cvt_pk_bf16(acc[m][2], acc[m][3]);
  }
  #pragma unroll
  for (int s = 0; s < 2; s++) {
    int t00 = __builtin_amdgcn_ds_bpermute(srcA, pk[2 * s][0]);
    int t01 = __builtin_amdgcn_ds_bpermute(srcA, pk[2 * s + 1][0]);
    int t10 = __builtin_amdgcn_ds_bpermute(srcA, pk[2 * s][1]);
    int t11 = __builtin_amdgcn_ds_bpermute(srcA, pk[2 * s + 1][1]);
    int t20 = __builtin_amdgcn_ds_bpermute(srcB, pk[2 * s][0]);
    int t21 = __builtin_amdgcn_ds_bpermute(srcB, pk[2 * s + 1][0]);
    int t30 = __builtin_amdgcn_ds_bpermute(srcB, pk[2 * s][1]);
    int t31 = __builtin_amdgcn_ds_bpermute(srcB, pk[2 * s + 1][1]);
    U4 u;
    u.u[0] = hi ? t01 : t00;
    u.u[1] = hi ? t11 : t10;
    u.u[2] = hi ? t21 : t20;
    u.u[3] = hi ? t31 : t30;
    Bf[s] = u.v;
  }
}

// ------- all-register MFMA MLP, 32 points/wave (round-16 verified body) -----
__global__ __launch_bounds__(256) void mlp_mfma32_kernel(
    const float* __restrict__ encpart, const float* __restrict__ zpart,
    const unsigned short* __restrict__ Wfrag,
    const float* __restrict__ W_out1, const float* __restrict__ W_out2,
    const float* __restrict__ mp, const float* __restrict__ orient,
    const float* __restrict__ amp, const float* __restrict__ ampvar,
    float4* __restrict__ rec, int* __restrict__ stripCntSeg,
    float* __restrict__ out_fp, float* __restrict__ out_disp) {
  __shared__ int h16[16];
  int tid = threadIdx.x;
  int lane = tid & 63;
  int wave = tid >> 6;
  int wid = blockIdx.x * 4 + wave;            // 0..16383
  int b = __builtin_amdgcn_readfirstlane(wid >> 9);
  int pbase = (wid & 511) * 32;
  int g = lane >> 4;
  int p0 = pbase + (lane & 15);
  int p1 = p0 + 16;

  if (tid < 16) h16[tid] = 0;
  __syncthreads();

  union U4 { int u[4]; v8s v; };

  v8s Bf0[2], Bf1[2];
  #pragma unroll
  for (int s = 0; s < 2; s++) {
    int k0 = s * 32 + g * 8;
    const float4* z4 = (const float4*)(zpart + b * 64 + k0);
    float4 z0 = z4[0], z1 = z4[1];
    {
      const float4* e4 = (const float4*)(encpart + (size_t)p0 * 64 + k0);
      float4 e0 = e4[0], e1 = e4[1];
      U4 u;
      u.u[0] = cvt_pk_bf16(e0.x + z0.x, e0.y + z0.y);
      u.u[1] = cvt_pk_bf16(e0.z + z0.z, e0.w + z0.w);
      u.u[2] = cvt_pk_bf16(e1.x + z1.x, e1.y + z1.y);
      u.u[3] = cvt_pk_bf16(e1.z + z1.z, e1.w + z1.w);
      Bf0[s] = u.v;
    }
    {
      const float4* e4 = (const float4*)(encpart + (size_t)p1 * 64 + k0);
      float4 e0 = e4[0], e1 = e4[1];
      U4 u;
      u.u[0] = cvt_pk_bf16(e0.x + z0.x, e0.y + z0.y);
      u.u[1] = cvt_pk_bf16(e0.z + z0.z, e0.w + z0.w);
      u.u[2] = cvt_pk_bf16(e1.x + z1.x, e1.y + z1.y);
      u.u[3] = cvt_pk_bf16(e1.z + z1.z, e1.w + z1.w);
      Bf1[s] = u.v;
    }
  }

  int srcA = ((((lane >> 4) & 1) * 32) + (lane & 15)) << 2;
  int srcB = srcA + 64;
  bool hi = (lane >> 5) & 1;

  const v8s* WfragV = (const v8s*)Wfrag;
  v4f acc0[4], acc1[4];

  #pragma unroll 1
  for (int L = 0; L < 4; L++) {
    v8s Af[4][2];
    #pragma unroll
    for (int m = 0; m < 4; m++)
      #pragma unroll
      for (int s = 0; s < 2; s++)
        Af[m][s] = WfragV[(size_t)(((L * 4 + m) * 2 + s) * 64) + lane];

    #pragma unroll
    for (int m = 0; m < 4; m++) {
      acc0[m] = (v4f){0.f, 0.f, 0.f, 0.f};
      acc1[m] = (v4f){0.f, 0.f, 0.f, 0.f};
    }
    #pragma unroll
    for (int s = 0; s < 2; s++) {
      #pragma unroll
      for (int m = 0; m < 4; m++)
        acc0[m] = __builtin_amdgcn_mfma_f32_16x16x32_bf16(Af[m][s], Bf0[s], acc0[m], 0, 0, 0);
      #pragma unroll
      for (int m = 0; m < 4; m++)
        acc1[m] = __builtin_amdgcn_mfma_f32_16x16x32_bf16(Af[m][s], Bf1[s], acc1[m], 0, 0, 0);
    }

    #pragma unroll
    for (int m = 0; m < 4; m++)
      #pragma unroll
      for (int r = 0; r < 4; r++) {
        acc0[m][r] = elu_f(acc0[m][r]);
        acc1[m][r] = elu_f(acc1[m][r]);
      }

    if (L < 3) {
      regroup(acc0, Bf0, srcA, srcB, hi);
      regroup(acc1, Bf1, srcA, srcB, hi);
    }
  }

  float o00 = 0.f, o01 = 0.f, o02 = 0.f;
  float o10 = 0.f, o11 = 0.f, o12 = 0.f;
  #pragma unroll
  for (int m = 0; m < 4; m++) {
    int jb = m * 16 + g * 4;
    const float4* w4 = (const float4*)(W_out1 + jb * 3);
    float4 wa = w4[0], wb = w4[1], wc = w4[2];
    o00 += acc0[m][0] * wa.x + acc0[m][1] * wa.w + acc0[m][2] * wb.z + acc0[m][3] * wc.y;
    o01 += acc0[m][0] * wa.y + acc0[m][1] * wb.x + acc0[m][2] * wb.w + acc0[m][3] * wc.z;
    o02 += acc0[m][0] * wa.z + acc0[m][1] * wb.y + acc0[m][2] * wc.x + acc0[m][3] * wc.w;
    o10 += acc1[m][0] * wa.x + acc1[m][1] * wa.w + acc1[m][2] * wb.z + acc1[m][3] * wc.y;
    o11 += acc1[m][0] * wa.y + acc1[m][1] * wb.x + acc1[m][2] * wb.w + acc1[m][3] * wc.z;
    o12 += acc1[m][0] * wa.z + acc1[m][1] * wb.y + acc1[m][2] * wc.x + acc1[m][3] * wc.w;
  }
  o00 += __shfl_xor(o00, 16, 64); o00 += __shfl_xor(o00, 32, 64);
  o01 += __shfl_xor(o01, 16, 64); o01 += __shfl_xor(o01, 32, 64);
  o02 += __shfl_xor(o02, 16, 64); o02 += __shfl_xor(o02, 32, 64);
  o10 += __shfl_xor(o10, 16, 64); o10 += __shfl_xor(o10, 32, 64);
  o11 += __shfl_xor(o11, 16, 64); o11 += __shfl_xor(o11, 32, 64);
  o12 += __shfl_xor(o12, 16, 64); o12 += __shfl_xor(o12, 32, 64);

  o00 = elu_f(o00); o01 = elu_f(o01); o02 = elu_f(o02);
  o10 = elu_f(o10); o11 = elu_f(o11); o12 = elu_f(o12);

  float W0 = W_out2[0], W1 = W_out2[1], W2 = W_out2[2];
  float W3 = W_out2[3], W4 = W_out2[4], W5 = W_out2[5];
  float W6 = W_out2[6], W7 = W_out2[7], W8 = W_out2[8];

  float d00 = o00 * W0 + o01 * W3 + o02 * W6;
  float d01 = o00 * W1 + o01 * W4 + o02 * W7;
  float d02 = o00 * W2 + o01 * W5 + o02 * W8;
  float d10 = o10 * W0 + o11 * W3 + o12 * W6;
  float d11 = o10 * W1 + o11 * W4 + o12 * W7;
  float d12 = o10 * W2 + o11 * W5 + o12 * W8;

  float m00 = mp[p0 * 3 + 0], m01 = mp[p0 * 3 + 1], m02 = mp[p0 * 3 + 2];
  float m10 = mp[p1 * 3 + 0], m11 = mp[p1 * 3 + 1], m12 = mp[p1 * 3 + 2];
  float f00 = m00 + d00, f01 = m01 + d01, f02 = m02 + d02;
  float f10 = m10 + d10, f11 = m11 + d11, f12 = m12 + d12;

  size_t ob0 = ((size_t)b * Pn + p0) * 3;
  size_t ob1 = ((size_t)b * Pn + p1) * 3;
  if (g == 2) {
    out_disp[ob0 + 0] = d00; out_disp[ob0 + 1] = d01; out_disp[ob0 + 2] = d02;
    out_fp[ob0 + 0] = f00; out_fp[ob0 + 1] = f01; out_fp[ob0 + 2] = f02;
  }
  if (g == 3) {
    out_disp[ob1 + 0] = d10; out_disp[ob1 + 1] = d11; out_disp[ob1 + 2] = d12;
    out_fp[ob1 + 0] = f10; out_fp[ob1 + 1] = f11; out_fp[ob1 + 2] = f12;
  }

  const float* R = orient + b * 9;
  float px0 = R[0] * f00 + R[1] * f01 + R[2] * f02;
  float py0 = R[3] * f00 + R[4] * f01 + R[5] * f02;
  float px1 = R[0] * f10 + R[1] * f11 + R[2] * f12;
  float py1 = R[3] * f10 + R[4] * f11 + R[5] * f12;

  float a00 = ampvar[p0], a01 = ampvar[Pn + p0];
  float mx0 = fmaxf(a00, a01);
  float e00 = __expf(a00 - mx0), e01 = __expf(a01 - mx0);
  float inv0 = 1.0f / (e00 + e01);
  float w00a = amp[p0] * e00 * inv0;
  float w01a = amp[Pn + p0] * e01 * inv0;
  float a10 = ampvar[p1], a11 = ampvar[Pn + p1];
  float mx1 = fmaxf(a10, a11);
  float e10 = __expf(a10 - mx1), e11 = __expf(a11 - mx1);
  float inv1 = 1.0f / (e10 + e11);
  float w10a = amp[p1] * e10 * inv1;
  float w11a = amp[Pn + p1] * e11 * inv1;

  float pxp0 = fminf(fmaxf((px0 + 0.5f) * 256.0f, 0.0f), 254.999f);
  float pyp0 = fminf(fmaxf((py0 + 0.5f) * 256.0f, 0.0f), 254.999f);
  float pxp1 = fminf(fmaxf((px1 + 0.5f) * 256.0f, 0.0f), 254.999f);
  float pyp1 = fminf(fmaxf((py1 + 0.5f) * 256.0f, 0.0f), 254.999f);

  if (g == 0) {
    atomicAdd(&h16[((int)pyp0) >> 4], 1);
    rec[(size_t)b * Pn + p0] = make_float4(pxp0, pyp0, w00a, w01a);
  }
  if (g == 1) {
    atomicAdd(&h16[((int)pyp1) >> 4], 1);
    rec[(size_t)b * Pn + p1] = make_float4(pxp1, pyp1, w10a, w11a);
  }
  __syncthreads();
  int bblk = __builtin_amdgcn_readfirstlane(blockIdx.x >> 7);
  int seg  = __builtin_amdgcn_readfirstlane((blockIdx.x & 127) >> 4);
  if (tid < 16 && h16[tid] != 0)
    atomicAdd(&stripCntSeg[(bblk * 8 + seg) * 16 + tid], h16[tid]);
}

// -------- scatter16: per-(b,seg), group records by y-strip (LDS cursors) ----
__global__ __launch_bounds__(256) void scatter16_kernel(const float4* __restrict__ rec,
                                                        const int* __restrict__ stripCntSeg,
                                                        float4* __restrict__ sorted) {
  __shared__ int tot[16], start[16], cur[16];
  int blk = blockIdx.x;
  int b = blk >> 3, seg = blk & 7;
  int tid = threadIdx.x;
  int myoff = 0;
  if (tid < 16) {
    int acc = 0, so = 0;
    #pragma unroll
    for (int s = 0; s < 8; s++) {
      int c = stripCntSeg[(b * 8 + s) * 16 + tid];
      if (s < seg) so += c;
      acc += c;
    }
    tot[tid] = acc; myoff = so;
  }
  __syncthreads();
  if (tid == 0) { int a = 0; for (int i = 0; i < 16; i++) { start[i] = a; a += tot[i]; } }
  __syncthreads();
  if (tid < 16) cur[tid] = start[tid] + myoff;
  __syncthreads();
  int base = seg * 2048;
  for (int i = base + tid; i < base + 2048; i += 256) {
    float4 r = rec[(size_t)b * Pn + i];
    int strip = ((int)r.y) >> 4;
    int slot = atomicAdd(&cur[strip], 1);
    sorted[(size_t)b * Pn + slot] = r;
  }
}

// ------- F1 (fused splat + row FFT): block = (b, 8-row chunk), 1024 blocks.
// Strip-sorted contiguous reads; native int LDS atomics (fixed-point x2048);
// PAIRED fence-only float2 FFTs (2 independent rows interleaved per wave);
// Hermitian unpack; transposed write [kx][y], kx in [0,132). -----------------
__global__ __launch_bounds__(256) void splat_fft_rows_T(const float4* __restrict__ sorted,
                                                        const int* __restrict__ stripCntSeg,
                                                        float2* __restrict__ ws1) {
  __shared__ float2 scx[8][257];
  __shared__ float2 tw[128];
  __shared__ int tot[16], start[16];
  int tid = threadIdx.x;
  int lane = tid & 63, wave = tid >> 6;
  int blk = blockIdx.x;
  int chunk = blk & 31, b = blk >> 5;
  for (int t = tid; t < 128; t += 256) {
    float ang = -TWO_PI_F * (float)t / 256.0f;
    tw[t] = make_float2(cosf(ang), sinf(ang));
  }
  if (tid < 16) {
    int acc = 0;
    #pragma unroll
    for (int s = 0; s < 8; s++) acc += stripCntSeg[(b * 8 + s) * 16 + tid];
    tot[tid] = acc;
  }
  float2* fc = &scx[0][0];
  int* ip = (int*)fc;
  for (int j = tid; j < 8 * 257; j += 256) fc[j] = make_float2(0.f, 0.f);
  __syncthreads();
  if (tid == 0) { int a = 0; for (int i = 0; i < 16; i++) { start[i] = a; a += tot[i]; } }
  __syncthreads();

  int ybase = chunk * 8;
  int loS = (chunk > 0) ? ((ybase - 1) >> 4) : 0;
  int hiS = (ybase + 7) >> 4;
  int lo = start[loS];
  int hi = start[hiS] + tot[hiS];
  const float4* rb = sorted + (size_t)b * Pn;
  for (int i = lo + tid; i < hi; i += 256) {
    float4 r = rb[i];
    int y0 = (int)r.y;
    int d = y0 - ybase;
    if (d >= -1 && d <= 7) {
      int x0 = (int)r.x;
      int x1 = x0 + 1;                       // x0 <= 254 by clamp
      float fx = r.x - (float)x0, fy = r.y - (float)y0;
      float w00 = (1.f - fx) * (1.f - fy), w10 = fx * (1.f - fy);
      float w01 = (1.f - fx) * fy,         w11 = fx * fy;
      if (d >= 0) {
        int e0 = (d * 257 + x0) * 2, e1 = (d * 257 + x1) * 2;
        atomicAdd(&ip[e0],     __float2int_rn(r.z * w00 * SPLAT_SCALE));
        atomicAdd(&ip[e0 + 1], __float2int_rn(r.w * w00 * SPLAT_SCALE));
        atomicAdd(&ip[e1],     __float2int_rn(r.z * w10 * SPLAT_SCALE));
        atomicAdd(&ip[e1 + 1], __float2int_rn(r.w * w10 * SPLAT_SCALE));
      }
      if (d <= 6) {
        int e0 = ((d + 1) * 257 + x0) * 2, e1 = ((d + 1) * 257 + x1) * 2;
        atomicAdd(&ip[e0],     __float2int_rn(r.z * w01 * SPLAT_SCALE));
        atomicAdd(&ip[e0 + 1], __float2int_rn(r.w * w01 * SPLAT_SCALE));
        atomicAdd(&ip[e1],     __float2int_rn(r.z * w11 * SPLAT_SCALE));
        atomicAdd(&ip[e1 + 1], __float2int_rn(r.w * w11 * SPLAT_SCALE));
      }
    }
  }
  __syncthreads();
  for (int j = tid; j < 8 * 257; j += 256) {
    int2 v = ((const int2*)ip)[j];
    fc[j] = make_float2((float)v.x * SPLAT_INV, (float)v.y * SPLAT_INV);
  }
  __syncthreads();

  // paired wave-private FFTs (rows 2w, 2w+1), fence-only, complex layout
  fft256_c2(&scx[wave * 2][0], &scx[wave * 2 + 1][0], tw, lane, false);
  __syncthreads();
  // unpack: Z0 = (Z(k)+conj(Z(m)))/2, Z1 = -i/2 (Z(k)-conj(Z(m))), m=(256-k)&255
  #pragma unroll 1
  for (int ko = 0; ko < 5; ko++) {
    int kx = ko * 32 + (tid >> 3);
    int ysub = tid & 7;
    if (kx < KXD) {
      int m = (256 - kx) & 255;
      float2 zv = scx[ysub][kx];
      float2 mv = scx[ysub][m];
      float z0r = 0.5f * (zv.x + mv.x), z0i = 0.5f * (zv.y - mv.y);
      float z1r = 0.5f * (zv.y + mv.y), z1i = 0.5f * (mv.x - zv.x);
      size_t y = (size_t)(chunk * 8 + ysub);
      ws1[((size_t)(b * 2 + 0) * KXD + kx) * 256 + y] = make_float2(z0r, z0i);
      ws1[((size_t)(b * 2 + 1) * KXD + kx) * 256 + y] = make_float2(z1r, z1i);
    }
  }
}

// ------- F2: per kx line: PAIRED fwd y-FFT both classes, filter-combine,
//         phase_y, inv y-FFT; write line kx AND conjugate mirror, [y][kx] ----
__global__ __launch_bounds__(256) void fft_mid_T(const float2* __restrict__ ws1,
                                                 float2* __restrict__ A2,
                                                 const float* __restrict__ shift,
                                                 const float* __restrict__ Aarr,
                                                 const float* __restrict__ Bparr) {
  __shared__ float2 scx[4][257], wcx[4][257];
  __shared__ float2 tw[128];
  int tid = threadIdx.x;
  int lane = tid & 63, wave = tid >> 6;
  int blk = blockIdx.x;
  int b = blk / 33, c33 = blk % 33;
  int kx = c33 * 4 + wave;                   // 0..131
  for (int t = tid; t < 128; t += 256) {
    float ang = -TWO_PI_F * (float)t / 256.0f;
    tw[t] = make_float2(cosf(ang), sinf(ang));
  }
  __syncthreads();
  float A0 = Aarr[0], A1 = Aarr[1], B0 = Bparr[0], B1 = Bparr[1];
  float sy = shift[b * 2 + 1];
  const float2* r0 = ws1 + ((size_t)(b * 2 + 0) * KXD + kx) * 256;
  const float2* r1 = ws1 + ((size_t)(b * 2 + 1) * KXD + kx) * 256;
  #pragma unroll
  for (int q = 0; q < 4; q++) {
    int i = lane + q * 64;
    scx[wave][i] = r0[i];
    wcx[wave][i] = r1[i];
  }
  wave_lds_fence();
  // paired independent forward FFTs: interleaved, one fence per stage
  fft256_c2(&scx[wave][0], &wcx[wave][0], tw, lane, false);
  float rx = (kx <= 128) ? (float)kx : (float)(256 - kx);
  #pragma unroll
  for (int q = 0; q < 4; q++) {
    int ky = lane + q * 64;
    float ry = (ky <= 128) ? (float)ky : (float)(256 - ky);
    float R = sqrtf(rx * rx + ry * ry);
    float FF0 = A0 * A0 * __expf(-B0 * B0 * R);
    float FF1 = A1 * A1 * __expf(-B1 * B1 * R);
    float2 sv = scx[wave][ky];
    float2 wv = wcx[wave][ky];
    float Gr = FF0 * sv.x + FF1 * wv.x;
    float Gi = FF0 * sv.y + FF1 * wv.y;
    float fk = (float)((ky < 128) ? ky : ky - 256) / 256.0f;
    float th = -TWO_PI_F * fk * sy;
    float cc = __cosf(th), ss = __sinf(th);
    scx[wave][ky] = make_float2(Gr * cc - Gi * ss, Gr * ss + Gi * cc);
  }
  wave_lds_fence();
  fft256_c(&scx[wave][0], tw, lane, true);
  __syncthreads();   // cross-wave transposed write below
  const float inv = 1.0f / 256.0f;
  int kx0 = c33 * 4;
  #pragma unroll 1
  for (int yo = 0; yo < 4; yo++) {
    int ksub = tid & 3;
    int y = yo * 64 + (tid >> 2);
    int kxw = kx0 + ksub;
    float2 v = scx[ksub][y];
    float vr = v.x * inv, vi = v.y * inv;
    if (kxw <= 128)
      A2[(size_t)b * 65536 + (size_t)y * 256 + kxw] = make_float2(vr, vi);
    if (kxw >= 1 && kxw <= 127)
      A2[(size_t)b * 65536 + (size_t)y * 256 + (256 - kxw)] = make_float2(vr, -vi);
  }
}

// ------- F3: packed pair inverse x-FFT (Hermitian projection via shuffles) --
__global__ __launch_bounds__(256) void fft_final_pk(const float2* __restrict__ A2t,
                                                    const float* __restrict__ shift,
                                                    float* __restrict__ out_imgs) {
  __shared__ float2 X[4][257];
  __shared__ float2 tw[128];
  int tid = threadIdx.x;
  int lane = tid & 63, wave = tid >> 6;
  int blk = blockIdx.x;
  int b = blk >> 5, grp = blk & 31;
  int y0 = grp * 8 + wave * 2;
  int y1 = y0 + 1;
  for (int t = tid; t < 128; t += 256) {
    float ang = -TWO_PI_F * (float)t / 256.0f;
    tw[t] = make_float2(cosf(ang), sinf(ang));
  }
  __syncthreads();   // twiddles written by waves 0-1, read by all
  float sx = shift[b * 2 + 0];
  const float2* row0 = A2t + (size_t)b * 65536 + (size_t)y0 * 256;
  const float2* row1 = A2t + (size_t)b * 65536 + (size_t)y1 * 256;
  float g0r[4], g0i[4], g1r[4], g1i[4];
  #pragma unroll
  for (int q = 0; q < 4; q++) {
    int k = lane + q * 64;
    float2 v0 = row0[k], v1 = row1[k];
    float fk = (float)((k < 128) ? k : k - 256) / 256.0f;
    float th = -TWO_PI_F * fk * sx;
    float c = __cosf(th), s = __sinf(th);
    g0r[q] = v0.x * c - v0.y * s;  g0i[q] = v0.x * s + v0.y * c;
    g1r[q] = v1.x * c - v1.y * s;  g1i[q] = v1.x * s + v1.y * c;
  }
  int src = (64 - lane) & 63;
  float s0r[4], s0i[4], s1r[4], s1i[4];
  #pragma unroll
  for (int j = 0; j < 4; j++) {
    s0r[j] = __shfl(g0r[j], src, 64);  s0i[j] = __shfl(g0i[j], src, 64);
    s1r[j] = __shfl(g1r[j], src, 64);  s1i[j] = __shfl(g1i[j], src, 64);
  }
  bool l0 = (lane == 0);
  #pragma unroll
  for (int q = 0; q < 4; q++) {
    const int qa = 3 - q;          // lane >= 1
    const int qb = (4 - q) & 3;    // lane == 0
    float m0r = l0 ? s0r[qb] : s0r[qa];
    float m0i = l0 ? s0i[qb] : s0i[qa];
    float m1r = l0 ? s1r[qb] : s1r[qa];
    float m1i = l0 ? s1i[qb] : s1i[qa];
    float h0r = 0.5f * (g0r[q] + m0r), h0i = 0.5f * (g0i[q] - m0i);
    float h1r = 0.5f * (g1r[q] + m1r), h1i = 0.5f * (g1i[q] - m1i);
    int k = lane + q * 64;
    X[wave][k] = make_float2(h0r - h1i, h0i + h1r);   // pack: hg0 + i*hg1
  }
  wave_lds_fence();
  fft256_c(&X[wave][0], tw, lane, true);
  const float inv = 1.0f / 256.0f;
  float* o0 = out_imgs + (size_t)b * 65536 + (size_t)y0 * 256;
  float* o1 = out_imgs + (size_t)b * 65536 + (size_t)y1 * 256;
  #pragma unroll
  for (int q = 0; q < 4; q++) {
    int x = lane + q * 64;
    float2 v = X[wave][x];
    o0[x] = v.x * inv;
    o1[x] = v.y * inv;
  }
}

// ---------------- launch ----------------
extern "C" void kernel_launch(void* const* d_in, const int* in_sizes, int n_in,
                              void* d_out, int out_size, void* d_ws, size_t ws_size,
                              hipStream_t stream) {
  (void)in_sizes; (void)n_in; (void)out_size; (void)ws_size;
  const float* z       = (const float*)d_in[0];
  const float* orient  = (const float*)d_in[1];
  const float* shift   = (const float*)d_in[2];
  const float* mp      = (const float*)d_in[3];
  const float* W_in    = (const float*)d_in[4];
  const float* W_layers= (const float*)d_in[5];
  const float* W_out1  = (const float*)d_in[6];
  const float* W_out2  = (const float*)d_in[7];
  const float* amp     = (const float*)d_in[8];
  const float* ampvar  = (const float*)d_in[9];
  const float* Aarr    = (const float*)d_in[10];
  const float* Bparr   = (const float*)d_in[11];

  char* ws0 = (char*)d_ws;
  // Region0 (sequential lifetimes): encpart(4MB, enc->mlp) -> A2(16.8MB, F2->F3)
  float*  encpart = (float*)ws0;
  float2* A2      = (float2*)ws0;
  // RegionB at +19MiB; all buffers disjoint.
  char* wsB = ws0 + 19922944;
  float2* ws1     = (float2*)wsB;                         // 17,301,504 B (F1->F2)
  float4* rec     = (float4*)(wsB + 17301504);            // 8 MiB (mlp->scatter)
  float4* sorted  = (float4*)(wsB + 25690112);            // 8 MiB (scatter->F1)
  float*  zpart   = (float*)(wsB + 34078720);             // 8 KB
  unsigned short* Wfrag = (unsigned short*)(wsB + 34078720 + 8192);  // 32 KB
  int* stripCntSeg = (int*)(wsB + 34078720 + 40960);      // 16 KB

  float* out      = (float*)d_out;
  float* out_imgs = out;                               // [B][S][S]
  float* out_fp   = out + (size_t)Bn * Sn * Sn;        // [B][P][3]
  float* out_disp = out_fp + (size_t)Bn * Pn * 3;      // [B][P][3]

  enc_kernel<<<Pn / 64, 64, 0, stream>>>(mp, W_in, encpart);
  prep_kernel<<<16, 256, 0, stream>>>(z, W_in, W_layers, zpart, Wfrag, stripCntSeg);
  mlp_mfma32_kernel<<<(Bn * Pn / 32) / 4, 256, 0, stream>>>(
      encpart, zpart, Wfrag, W_out1, W_out2, mp, orient, amp, ampvar,
      rec, stripCntSeg, out_fp, out_disp);
  scatter16_kernel<<<Bn * 8, 256, 0, stream>>>(rec, stripCntSeg, sorted);
  splat_fft_rows_T<<<Bn * 32, 256, 0, stream>>>(sorted, stripCntSeg, ws1);
  fft_mid_T<<<Bn * 33, 256, 0, stream>>>(ws1, A2, shift, Aarr, Bparr);
  fft_final_pk<<<Bn * 32, 256, 0, stream>>>(A2, shift, out_imgs);
}